// Round 5
// baseline (191.799 us; speedup 1.0000x reference)
//
#include <hip/hip_runtime.h>
#include <math.h>

#define Bb 4
#define Cc 192
#define NN 1024
#define HD 384
#define NH 4
#define FF 1536   // NH*HD
#define KN 16
#define BN_EPS 1e-5f

// one row of register-tile FMAs: acc.{x,y,z,w} += av * b.{x,y,z,w}
#define FMA_ROW(ACC, AV, B) \
  ACC.x = fmaf(AV, B.x, ACC.x); ACC.y = fmaf(AV, B.y, ACC.y); \
  ACC.z = fmaf(AV, B.z, ACC.z); ACC.w = fmaf(AV, B.w, ACC.w);

// ---------------------------------------------------------------- fc1 + BN (same math/order as R2: bits feed dist/topk)
__global__ __launch_bounds__(256) void k_fc1(
    const float* __restrict__ x, const float* __restrict__ W1,
    const float* __restrict__ b1, const float* __restrict__ bn1,
    float* __restrict__ y) {
  int nt = blockIdx.x, ct = blockIdx.y, b = blockIdx.z;
  int n0 = nt * 64, ct64 = ct * 64;
  __shared__ float As[64][64];   // [k][n]
  __shared__ float Bs[64][64];   // [k][c]
  int t = threadIdx.x;
  int tx = t & 15, ty = t >> 4;
  float4 acc[4];
#pragma unroll
  for (int i = 0; i < 4; ++i) acc[i] = {0.f, 0.f, 0.f, 0.f};
  for (int k0 = 0; k0 < Cc; k0 += 64) {
    __syncthreads();
#pragma unroll
    for (int i = 0; i < 4; ++i) {
      int fi = t * 4 + i;
      int r = fi >> 4, q = fi & 15;
      float4 av = *(const float4*)&x[((size_t)b * Cc + k0 + r) * NN + n0 + q * 4];
      *(float4*)&As[r][q * 4] = av;
      float4 bv = *(const float4*)&W1[(size_t)(ct64 + r) * Cc + k0 + q * 4];
      Bs[q * 4 + 0][r] = bv.x; Bs[q * 4 + 1][r] = bv.y;
      Bs[q * 4 + 2][r] = bv.z; Bs[q * 4 + 3][r] = bv.w;
    }
    __syncthreads();
#pragma unroll 8
    for (int k = 0; k < 64; ++k) {
      float4 a = *(const float4*)&As[k][ty * 4];
      float4 bv = *(const float4*)&Bs[k][tx * 4];
      FMA_ROW(acc[0], a.x, bv)
      FMA_ROW(acc[1], a.y, bv)
      FMA_ROW(acc[2], a.z, bv)
      FMA_ROW(acc[3], a.w, bv)
    }
  }
  float s[4], mm[4], be[4], bias[4];
#pragma unroll
  for (int jj = 0; jj < 4; ++jj) {
    int c = ct64 + tx * 4 + jj;
    s[jj]    = bn1[c] / sqrtf(bn1[3 * Cc + c] + BN_EPS);
    mm[jj]   = bn1[2 * Cc + c];
    be[jj]   = bn1[Cc + c];
    bias[jj] = b1[c];
  }
  float accm[4][4] = {
      {acc[0].x, acc[0].y, acc[0].z, acc[0].w},
      {acc[1].x, acc[1].y, acc[1].z, acc[1].w},
      {acc[2].x, acc[2].y, acc[2].z, acc[2].w},
      {acc[3].x, acc[3].y, acc[3].z, acc[3].w}};
#pragma unroll
  for (int ii = 0; ii < 4; ++ii) {
    int n = n0 + ty * 4 + ii;
    float4 o;
    o.x = (accm[ii][0] + bias[0] - mm[0]) * s[0] + be[0];
    o.y = (accm[ii][1] + bias[1] - mm[1]) * s[1] + be[1];
    o.z = (accm[ii][2] + bias[2] - mm[2]) * s[2] + be[2];
    o.w = (accm[ii][3] + bias[3] - mm[3]) * s[3] + be[3];
    *(float4*)&y[((size_t)b * NN + n) * Cc + ct64 + tx * 4] = o;
  }
}

// ---------------------------------------------------------------- row sums of y^2 (unchanged)
__global__ __launch_bounds__(64) void k_sq(const float* __restrict__ y,
                                           float* __restrict__ sq) {
  int bn = blockIdx.x;
  int lane = threadIdx.x;
  const float* yp = y + (size_t)bn * Cc;
  float s = 0.f;
  for (int k = lane; k < Cc; k += 64) { float v = yp[k]; s = fmaf(v, v, s); }
#pragma unroll
  for (int off = 32; off; off >>= 1) s += __shfl_down(s, off);
  if (lane == 0) sq[bn] = s;
}

// ---------------------------------------------------------------- h = y @ Wg  (128x64 tile, 8x4/thread)
__global__ __launch_bounds__(256) void k_hgemm(const float* __restrict__ y,
                                               const float* __restrict__ Wg,
                                               float* __restrict__ h) {
  int r0 = blockIdx.x * 128, c0 = blockIdx.y * 64;
  __shared__ float As[64][128];   // [k][row] 32KB
  __shared__ float Bs[64][64];    // [k][col] 16KB
  int t = threadIdx.x;
  int tx = t & 15, ty = t >> 4;
  float4 acc[8];
#pragma unroll
  for (int i = 0; i < 8; ++i) acc[i] = {0.f, 0.f, 0.f, 0.f};
  for (int k0 = 0; k0 < Cc; k0 += 64) {
    __syncthreads();
#pragma unroll
    for (int i = 0; i < 8; ++i) {                 // A: 128 rows x 64k, transpose-stage
      int fi = i * 256 + t;
      int r = fi >> 4, j = fi & 15;
      float4 av = *(const float4*)&y[(size_t)(r0 + r) * Cc + k0 + j * 4];
      As[j * 4 + 0][r] = av.x; As[j * 4 + 1][r] = av.y;
      As[j * 4 + 2][r] = av.z; As[j * 4 + 3][r] = av.w;
    }
#pragma unroll
    for (int i = 0; i < 4; ++i) {                 // B: 64k x 64c, direct
      int fi = i * 256 + t;
      int kk = fi >> 4, c4 = fi & 15;
      *(float4*)&Bs[kk][c4 * 4] =
          *(const float4*)&Wg[(size_t)(k0 + kk) * FF + c0 + c4 * 4];
    }
    __syncthreads();
#pragma unroll 8
    for (int k = 0; k < 64; ++k) {
      float4 a0 = *(const float4*)&As[k][ty * 4];
      float4 a1 = *(const float4*)&As[k][64 + ty * 4];
      float4 b  = *(const float4*)&Bs[k][tx * 4];
      FMA_ROW(acc[0], a0.x, b)
      FMA_ROW(acc[1], a0.y, b)
      FMA_ROW(acc[2], a0.z, b)
      FMA_ROW(acc[3], a0.w, b)
      FMA_ROW(acc[4], a1.x, b)
      FMA_ROW(acc[5], a1.y, b)
      FMA_ROW(acc[6], a1.z, b)
      FMA_ROW(acc[7], a1.w, b)
    }
  }
#pragma unroll
  for (int ii = 0; ii < 8; ++ii) {
    int r = r0 + ((ii < 4) ? (ty * 4 + ii) : (64 + ty * 4 + ii - 4));
    *(float4*)&h[(size_t)r * FF + c0 + tx * 4] = acc[ii];
  }
}

// ---------------------------------------------------------------- a_src / a_dst (unchanged)
__global__ __launch_bounds__(256) void k_attn_coef(
    const float* __restrict__ h, const float* __restrict__ att_src,
    const float* __restrict__ att_dst, float* __restrict__ asrc,
    float* __restrict__ adst) {
  int bn = blockIdx.x;
  int head = threadIdx.x / 64, lane = threadIdx.x % 64;
  const float* hp = h + (size_t)bn * FF + head * HD;
  const float* as = att_src + head * HD;
  const float* ad = att_dst + head * HD;
  float s1 = 0.f, s2 = 0.f;
  for (int d = lane; d < HD; d += 64) {
    float v = hp[d];
    s1 = fmaf(v, as[d], s1);
    s2 = fmaf(v, ad[d], s2);
  }
#pragma unroll
  for (int off = 32; off; off >>= 1) {
    s1 += __shfl_down(s1, off);
    s2 += __shfl_down(s2, off);
  }
  if (lane == 0) {
    asrc[bn * NH + head] = s1;
    adst[bn * NH + head] = s2;
  }
}

// ---------------------------------------------------------------- pairwise distances (128x64, 8x4/thread)
__global__ __launch_bounds__(256) void k_dist(const float* __restrict__ y,
                                              const float* __restrict__ sq,
                                              float* __restrict__ dist) {
  int b = blockIdx.z;
  int n0 = blockIdx.y * 128, m0 = blockIdx.x * 64;
  __shared__ float As[64][128];   // [k][n] 32KB
  __shared__ float Bs[64][64];    // [k][m] 16KB
  const float* yb = y + (size_t)b * NN * Cc;
  int t = threadIdx.x;
  int tx = t & 15, ty = t >> 4;
  float4 acc[8];
#pragma unroll
  for (int i = 0; i < 8; ++i) acc[i] = {0.f, 0.f, 0.f, 0.f};
  for (int k0 = 0; k0 < Cc; k0 += 64) {
    __syncthreads();
#pragma unroll
    for (int i = 0; i < 8; ++i) {                 // A rows n0..n0+127, transpose
      int fi = i * 256 + t;
      int r = fi >> 4, j = fi & 15;
      float4 av = *(const float4*)&yb[(size_t)(n0 + r) * Cc + k0 + j * 4];
      As[j * 4 + 0][r] = av.x; As[j * 4 + 1][r] = av.y;
      As[j * 4 + 2][r] = av.z; As[j * 4 + 3][r] = av.w;
    }
#pragma unroll
    for (int i = 0; i < 4; ++i) {                 // B rows m0..m0+63, transpose
      int fi = i * 256 + t;
      int m = fi >> 4, j = fi & 15;
      float4 bv = *(const float4*)&yb[(size_t)(m0 + m) * Cc + k0 + j * 4];
      Bs[j * 4 + 0][m] = bv.x; Bs[j * 4 + 1][m] = bv.y;
      Bs[j * 4 + 2][m] = bv.z; Bs[j * 4 + 3][m] = bv.w;
    }
    __syncthreads();
#pragma unroll 8
    for (int k = 0; k < 64; ++k) {
      float4 a0 = *(const float4*)&As[k][ty * 4];
      float4 a1 = *(const float4*)&As[k][64 + ty * 4];
      float4 b  = *(const float4*)&Bs[k][tx * 4];
      FMA_ROW(acc[0], a0.x, b)
      FMA_ROW(acc[1], a0.y, b)
      FMA_ROW(acc[2], a0.z, b)
      FMA_ROW(acc[3], a0.w, b)
      FMA_ROW(acc[4], a1.x, b)
      FMA_ROW(acc[5], a1.y, b)
      FMA_ROW(acc[6], a1.z, b)
      FMA_ROW(acc[7], a1.w, b)
    }
  }
#pragma unroll
  for (int ii = 0; ii < 8; ++ii) {
    int n = n0 + ((ii < 4) ? (ty * 4 + ii) : (64 + ty * 4 + ii - 4));
    float sn = sq[b * NN + n];
    int mbase = m0 + tx * 4;
    float av[4] = {acc[ii].x, acc[ii].y, acc[ii].z, acc[ii].w};
    float4 o;
    o.x = sn + sq[b * NN + mbase + 0] - 2.f * av[0];
    o.y = sn + sq[b * NN + mbase + 1] - 2.f * av[1];
    o.z = sn + sq[b * NN + mbase + 2] - 2.f * av[2];
    o.w = sn + sq[b * NN + mbase + 3] - 2.f * av[3];
    *(float4*)&dist[((size_t)b * NN + n) * NN + mbase] = o;
  }
}

// ---------------------------------------------------------------- top-16 smallest per row (unchanged)
__global__ __launch_bounds__(64) void k_topk(const float* __restrict__ dist,
                                             int* __restrict__ idx) {
  int bn = blockIdx.x;
  int lane = threadIdx.x;
  const float4* dp = (const float4*)(dist + (size_t)bn * NN);
  float dv[16];
#pragma unroll
  for (int q = 0; q < 4; ++q) {
    float4 v = dp[lane + 64 * q];
    dv[q * 4 + 0] = v.x; dv[q * 4 + 1] = v.y;
    dv[q * 4 + 2] = v.z; dv[q * 4 + 3] = v.w;
  }
  for (int sel = 0; sel < KN; ++sel) {
    float bv = INFINITY;
    int bi = 0x7fffffff;
#pragma unroll
    for (int q = 0; q < 4; ++q)
#pragma unroll
      for (int j = 0; j < 4; ++j) {
        int m = (lane + 64 * q) * 4 + j;
        float v = dv[q * 4 + j];
        if (v < bv || (v == bv && m < bi)) { bv = v; bi = m; }
      }
#pragma unroll
    for (int off = 32; off; off >>= 1) {
      float ov = __shfl_xor(bv, off);
      int oi   = __shfl_xor(bi, off);
      if (ov < bv || (ov == bv && oi < bi)) { bv = ov; bi = oi; }
    }
    if (lane == 0) idx[bn * KN + sel] = bi;
#pragma unroll
    for (int q = 0; q < 4; ++q)
#pragma unroll
      for (int j = 0; j < 4; ++j)
        if ((lane + 64 * q) * 4 + j == bi) dv[q * 4 + j] = INFINITY;
  }
}

// ---------------------------------------------------------------- GAT aggregate + BN + GELU (unchanged from R2)
__global__ __launch_bounds__(128, 4) void k_gat(
    const float* __restrict__ h, const float* __restrict__ asrc,
    const float* __restrict__ adst, const int* __restrict__ idx,
    const float* __restrict__ bg, const float* __restrict__ bng,
    float* __restrict__ g) {
  int bid = blockIdx.x;
  int bn = (bid & 7) * (Bb * NN / 8) + (bid >> 3);   // bijective XCD swizzle
  int b = bn / NN;
  __shared__ int nb[KN];
  __shared__ float attn[KN][NH];
  int t = threadIdx.x;
  if (t < KN) nb[t] = idx[bn * KN + t];
  __syncthreads();
  if (t < KN * NH) {
    int k = t % KN, hd = t / KN;
    float e = asrc[((size_t)b * NN + nb[k]) * NH + hd] +
              adst[(size_t)bn * NH + hd];
    e = (e >= 0.f) ? e : 0.2f * e;
    attn[k][hd] = e;
  }
  __syncthreads();
  if (t < NH) {
    float mx = -INFINITY;
    for (int k = 0; k < KN; ++k) mx = fmaxf(mx, attn[k][t]);
    float s = 0.f;
    for (int k = 0; k < KN; ++k) {
      float ev = expf(attn[k][t] - mx);
      attn[k][t] = ev;
      s += ev;
    }
    float inv = 1.f / s;
    for (int k = 0; k < KN; ++k) attn[k][t] *= inv;
  }
  __syncthreads();
  if (t < 96) {
    int d = t * 4;
    float4 acc = {0.f, 0.f, 0.f, 0.f};
#pragma unroll 4
    for (int k = 0; k < KN; ++k) {
      const float* hp = h + ((size_t)b * NN + nb[k]) * FF + d;
      float4 aw = *(const float4*)&attn[k][0];
      float4 h0 = *(const float4*)&hp[0];
      float4 h1 = *(const float4*)&hp[HD];
      float4 h2 = *(const float4*)&hp[2 * HD];
      float4 h3 = *(const float4*)&hp[3 * HD];
      acc.x = fmaf(aw.x, h0.x, acc.x); acc.x = fmaf(aw.y, h1.x, acc.x);
      acc.x = fmaf(aw.z, h2.x, acc.x); acc.x = fmaf(aw.w, h3.x, acc.x);
      acc.y = fmaf(aw.x, h0.y, acc.y); acc.y = fmaf(aw.y, h1.y, acc.y);
      acc.y = fmaf(aw.z, h2.y, acc.y); acc.y = fmaf(aw.w, h3.y, acc.y);
      acc.z = fmaf(aw.x, h0.z, acc.z); acc.z = fmaf(aw.y, h1.z, acc.z);
      acc.z = fmaf(aw.z, h2.z, acc.z); acc.z = fmaf(aw.w, h3.z, acc.z);
      acc.w = fmaf(aw.x, h0.w, acc.w); acc.w = fmaf(aw.y, h1.w, acc.w);
      acc.w = fmaf(aw.z, h2.w, acc.w); acc.w = fmaf(aw.w, h3.w, acc.w);
    }
    float o[4] = {acc.x, acc.y, acc.z, acc.w};
    float4 r;
    float* rp = (float*)&r;
#pragma unroll
    for (int j = 0; j < 4; ++j) {
      int dd = d + j;
      float val = o[j] * 0.25f + bg[dd];
      float sc = bng[dd] / sqrtf(bng[3 * HD + dd] + BN_EPS);
      val = (val - bng[2 * HD + dd]) * sc + bng[HD + dd];
      val = 0.5f * val * (1.f + erff(val * 0.7071067811865475f));
      rp[j] = val;
    }
    *(float4*)&g[(size_t)bn * HD + d] = r;
  }
}

// ---------------------------------------------------------------- fc2 + BN + residual + transpose (same math/order as R2)
__global__ __launch_bounds__(256) void k_fc2(
    const float* __restrict__ g, const float* __restrict__ W2,
    const float* __restrict__ b2, const float* __restrict__ bn2,
    const float* __restrict__ x, float* __restrict__ out) {
  int nt = blockIdx.x, ct = blockIdx.y, b = blockIdx.z;
  int n0 = nt * 64, c0 = ct * 64;
  __shared__ float As[64][64];   // [k][n]
  __shared__ float Bs[64][64];   // [k][c]
  int t = threadIdx.x;
  int tx = t & 15, ty = t >> 4;
  float4 acc[4];
#pragma unroll
  for (int i = 0; i < 4; ++i) acc[i] = {0.f, 0.f, 0.f, 0.f};
  for (int k0 = 0; k0 < HD; k0 += 64) {
    __syncthreads();
#pragma unroll
    for (int i = 0; i < 4; ++i) {
      int fi = t * 4 + i;
      int r = fi >> 4, q = fi & 15;
      float4 av = *(const float4*)&g[((size_t)b * NN + n0 + r) * HD + k0 + q * 4];
      As[q * 4 + 0][r] = av.x; As[q * 4 + 1][r] = av.y;
      As[q * 4 + 2][r] = av.z; As[q * 4 + 3][r] = av.w;
      float4 bv = *(const float4*)&W2[(size_t)(c0 + r) * HD + k0 + q * 4];
      Bs[q * 4 + 0][r] = bv.x; Bs[q * 4 + 1][r] = bv.y;
      Bs[q * 4 + 2][r] = bv.z; Bs[q * 4 + 3][r] = bv.w;
    }
    __syncthreads();
#pragma unroll 8
    for (int k = 0; k < 64; ++k) {
      float4 a = *(const float4*)&As[k][ty * 4];
      float4 bv = *(const float4*)&Bs[k][tx * 4];
      FMA_ROW(acc[0], a.x, bv)
      FMA_ROW(acc[1], a.y, bv)
      FMA_ROW(acc[2], a.z, bv)
      FMA_ROW(acc[3], a.w, bv)
    }
  }
  float accm[4][4] = {
      {acc[0].x, acc[0].y, acc[0].z, acc[0].w},
      {acc[1].x, acc[1].y, acc[1].z, acc[1].w},
      {acc[2].x, acc[2].y, acc[2].z, acc[2].w},
      {acc[3].x, acc[3].y, acc[3].z, acc[3].w}};
#pragma unroll
  for (int jj = 0; jj < 4; ++jj) {
    int c = c0 + tx * 4 + jj;
    float s  = bn2[c] / sqrtf(bn2[3 * Cc + c] + BN_EPS);
    float mm = bn2[2 * Cc + c];
    float be = bn2[Cc + c];
    float bias = b2[c];
    float4 res = *(const float4*)&x[((size_t)b * Cc + c) * NN + n0 + ty * 4];
    float4 o;
    o.x = (accm[0][jj] + bias - mm) * s + be + res.x;
    o.y = (accm[1][jj] + bias - mm) * s + be + res.y;
    o.z = (accm[2][jj] + bias - mm) * s + be + res.z;
    o.w = (accm[3][jj] + bias - mm) * s + be + res.w;
    *(float4*)&out[((size_t)b * Cc + c) * NN + n0 + ty * 4] = o;
  }
}

extern "C" void kernel_launch(void* const* d_in, const int* in_sizes, int n_in,
                              void* d_out, int out_size, void* d_ws, size_t ws_size,
                              hipStream_t stream) {
  const float* x       = (const float*)d_in[0];
  const float* W1      = (const float*)d_in[1];
  const float* b1      = (const float*)d_in[2];
  const float* bn1     = (const float*)d_in[3];
  const float* Wg      = (const float*)d_in[4];
  const float* att_src = (const float*)d_in[5];
  const float* att_dst = (const float*)d_in[6];
  const float* bg      = (const float*)d_in[7];
  const float* bng     = (const float*)d_in[8];
  const float* W2      = (const float*)d_in[9];
  const float* b2      = (const float*)d_in[10];
  const float* bn2     = (const float*)d_in[11];
  float* out = (float*)d_out;

  float* ws   = (float*)d_ws;
  float* y    = ws;                        // 786432
  float* h    = y + 786432;                // 6291456
  float* sq   = h + 6291456;               // 4096
  float* asrc = sq + 4096;                 // 16384
  float* adst = asrc + 16384;              // 16384
  float* dist = adst + 16384;              // 4194304
  float* g    = dist;                      // 1572864 (reuse; dist dead after topk)
  int*   idx  = (int*)(dist + 4194304);    // 65536 ints

  k_fc1<<<dim3(16, 3, 4), 256, 0, stream>>>(x, W1, b1, bn1, y);
  k_sq<<<Bb * NN, 64, 0, stream>>>(y, sq);
  k_hgemm<<<dim3(32, 24), 256, 0, stream>>>(y, Wg, h);
  k_attn_coef<<<Bb * NN, 256, 0, stream>>>(h, att_src, att_dst, asrc, adst);
  k_dist<<<dim3(16, 8, 4), 256, 0, stream>>>(y, sq, dist);
  k_topk<<<Bb * NN, 64, 0, stream>>>(dist, idx);
  k_gat<<<Bb * NN, 128, 0, stream>>>(h, asrc, adst, idx, bg, bng, g);
  k_fc2<<<dim3(16, 3, 4), 256, 0, stream>>>(g, W2, b2, bn2, x, out);
}

// Round 6
// 179.784 us; speedup vs baseline: 1.0668x; 1.0668x over previous
//
#include <hip/hip_runtime.h>
#include <math.h>

#define Bb 4
#define Cc 192
#define NN 1024
#define HD 384
#define NH 4
#define FF 1536   // NH*HD
#define KN 16
#define BN_EPS 1e-5f

// one row of register-tile FMAs: acc.{x,y,z,w} += av * b.{x,y,z,w}
#define FMA_ROW(ACC, AV, B) \
  ACC.x = fmaf(AV, B.x, ACC.x); ACC.y = fmaf(AV, B.y, ACC.y); \
  ACC.z = fmaf(AV, B.z, ACC.z); ACC.w = fmaf(AV, B.w, ACC.w);

// LDS row strides padded +4 floats: breaks bank alignment (stride%32==4)
// while keeping 16B alignment for b128 ops.
#define LDA 132   // for [64][128] tiles
#define LDB 68    // for [64][64] tiles

// ---------------------------------------------------------------- fc1 + BN
// y[b,n,c] = BN1( sum_k x[b,k,n]*W1[c,k] + b1[c] ); compute order identical to R2.
__global__ __launch_bounds__(256) void k_fc1(
    const float* __restrict__ x, const float* __restrict__ W1,
    const float* __restrict__ b1, const float* __restrict__ bn1,
    float* __restrict__ y) {
  int nt = blockIdx.x, ct = blockIdx.y, b = blockIdx.z;
  int n0 = nt * 64, ct64 = ct * 64;
  __shared__ float As[64][LDB];   // [k][n]
  __shared__ float Bs[64][LDB];   // [k][c]
  int t = threadIdx.x;
  int tx = t & 15, ty = t >> 4;
  float4 acc[4];
#pragma unroll
  for (int i = 0; i < 4; ++i) acc[i] = {0.f, 0.f, 0.f, 0.f};
  for (int k0 = 0; k0 < Cc; k0 += 64) {
    __syncthreads();
#pragma unroll
    for (int i = 0; i < 4; ++i) {
      int fi = i * 256 + t;
      int r = fi >> 4, q = fi & 15;          // 16 lanes share r, q=0..15 -> 2-way banks
      // A: x[b][k0+r][n0+q*4] direct (k-major), float4 write
      float4 av = *(const float4*)&x[((size_t)b * Cc + k0 + r) * NN + n0 + q * 4];
      *(float4*)&As[r][q * 4] = av;
      // B: W1[ct64+r][k0+q*4] -> transpose scalar writes
      float4 bv = *(const float4*)&W1[(size_t)(ct64 + r) * Cc + k0 + q * 4];
      Bs[q * 4 + 0][r] = bv.x; Bs[q * 4 + 1][r] = bv.y;
      Bs[q * 4 + 2][r] = bv.z; Bs[q * 4 + 3][r] = bv.w;
    }
    __syncthreads();
#pragma unroll 8
    for (int k = 0; k < 64; ++k) {
      float4 a = *(const float4*)&As[k][ty * 4];
      float4 bv = *(const float4*)&Bs[k][tx * 4];
      FMA_ROW(acc[0], a.x, bv)
      FMA_ROW(acc[1], a.y, bv)
      FMA_ROW(acc[2], a.z, bv)
      FMA_ROW(acc[3], a.w, bv)
    }
  }
  float s[4], mm[4], be[4], bias[4];
#pragma unroll
  for (int jj = 0; jj < 4; ++jj) {
    int c = ct64 + tx * 4 + jj;
    s[jj]    = bn1[c] / sqrtf(bn1[3 * Cc + c] + BN_EPS);
    mm[jj]   = bn1[2 * Cc + c];
    be[jj]   = bn1[Cc + c];
    bias[jj] = b1[c];
  }
  float accm[4][4] = {
      {acc[0].x, acc[0].y, acc[0].z, acc[0].w},
      {acc[1].x, acc[1].y, acc[1].z, acc[1].w},
      {acc[2].x, acc[2].y, acc[2].z, acc[2].w},
      {acc[3].x, acc[3].y, acc[3].z, acc[3].w}};
#pragma unroll
  for (int ii = 0; ii < 4; ++ii) {
    int n = n0 + ty * 4 + ii;
    float4 o;
    o.x = (accm[ii][0] + bias[0] - mm[0]) * s[0] + be[0];
    o.y = (accm[ii][1] + bias[1] - mm[1]) * s[1] + be[1];
    o.z = (accm[ii][2] + bias[2] - mm[2]) * s[2] + be[2];
    o.w = (accm[ii][3] + bias[3] - mm[3]) * s[3] + be[3];
    *(float4*)&y[((size_t)b * NN + n) * Cc + ct64 + tx * 4] = o;
  }
}

// ---------------------------------------------------------------- row sums of y^2 (unchanged)
__global__ __launch_bounds__(64) void k_sq(const float* __restrict__ y,
                                           float* __restrict__ sq) {
  int bn = blockIdx.x;
  int lane = threadIdx.x;
  const float* yp = y + (size_t)bn * Cc;
  float s = 0.f;
  for (int k = lane; k < Cc; k += 64) { float v = yp[k]; s = fmaf(v, v, s); }
#pragma unroll
  for (int off = 32; off; off >>= 1) s += __shfl_down(s, off);
  if (lane == 0) sq[bn] = s;
}

// ---------------------------------------------------------------- h = y @ Wg  (128x64 tile, 8x4/thread, padded LDS)
__global__ __launch_bounds__(256) void k_hgemm(const float* __restrict__ y,
                                               const float* __restrict__ Wg,
                                               float* __restrict__ h) {
  int r0 = blockIdx.x * 128, c0 = blockIdx.y * 64;
  __shared__ float As[64][LDA];   // [k][row]
  __shared__ float Bs[64][LDB];   // [k][col]
  int t = threadIdx.x;
  int tx = t & 15, ty = t >> 4;
  float4 acc[8];
#pragma unroll
  for (int i = 0; i < 8; ++i) acc[i] = {0.f, 0.f, 0.f, 0.f};
  for (int k0 = 0; k0 < Cc; k0 += 64) {
    __syncthreads();
#pragma unroll
    for (int i = 0; i < 8; ++i) {                 // A: 128 rows x 64k, transpose-stage
      int fi = i * 256 + t;
      int r = fi >> 4, j = fi & 15;               // 16 lanes share r; bank=(j*16+c*4+r)%32 -> 2-way
      float4 av = *(const float4*)&y[(size_t)(r0 + r) * Cc + k0 + j * 4];
      As[j * 4 + 0][r] = av.x; As[j * 4 + 1][r] = av.y;
      As[j * 4 + 2][r] = av.z; As[j * 4 + 3][r] = av.w;
    }
#pragma unroll
    for (int i = 0; i < 4; ++i) {                 // B: 64k x 64c, direct float4
      int fi = i * 256 + t;
      int kk = fi >> 4, c4 = fi & 15;
      *(float4*)&Bs[kk][c4 * 4] =
          *(const float4*)&Wg[(size_t)(k0 + kk) * FF + c0 + c4 * 4];
    }
    __syncthreads();
#pragma unroll 8
    for (int k = 0; k < 64; ++k) {
      float4 a0 = *(const float4*)&As[k][ty * 4];
      float4 a1 = *(const float4*)&As[k][64 + ty * 4];
      float4 b  = *(const float4*)&Bs[k][tx * 4];
      FMA_ROW(acc[0], a0.x, b)
      FMA_ROW(acc[1], a0.y, b)
      FMA_ROW(acc[2], a0.z, b)
      FMA_ROW(acc[3], a0.w, b)
      FMA_ROW(acc[4], a1.x, b)
      FMA_ROW(acc[5], a1.y, b)
      FMA_ROW(acc[6], a1.z, b)
      FMA_ROW(acc[7], a1.w, b)
    }
  }
#pragma unroll
  for (int ii = 0; ii < 8; ++ii) {
    int r = r0 + ((ii < 4) ? (ty * 4 + ii) : (64 + ty * 4 + ii - 4));
    *(float4*)&h[(size_t)r * FF + c0 + tx * 4] = acc[ii];
  }
}

// ---------------------------------------------------------------- a_src / a_dst (unchanged)
__global__ __launch_bounds__(256) void k_attn_coef(
    const float* __restrict__ h, const float* __restrict__ att_src,
    const float* __restrict__ att_dst, float* __restrict__ asrc,
    float* __restrict__ adst) {
  int bn = blockIdx.x;
  int head = threadIdx.x / 64, lane = threadIdx.x % 64;
  const float* hp = h + (size_t)bn * FF + head * HD;
  const float* as = att_src + head * HD;
  const float* ad = att_dst + head * HD;
  float s1 = 0.f, s2 = 0.f;
  for (int d = lane; d < HD; d += 64) {
    float v = hp[d];
    s1 = fmaf(v, as[d], s1);
    s2 = fmaf(v, ad[d], s2);
  }
#pragma unroll
  for (int off = 32; off; off >>= 1) {
    s1 += __shfl_down(s1, off);
    s2 += __shfl_down(s2, off);
  }
  if (lane == 0) {
    asrc[bn * NH + head] = s1;
    adst[bn * NH + head] = s2;
  }
}

// ---------------------------------------------------------------- pairwise distances (128x64, 8x4/thread, padded LDS)
__global__ __launch_bounds__(256) void k_dist(const float* __restrict__ y,
                                              const float* __restrict__ sq,
                                              float* __restrict__ dist) {
  int b = blockIdx.z;
  int n0 = blockIdx.y * 128, m0 = blockIdx.x * 64;
  __shared__ float As[64][LDA];   // [k][n]
  __shared__ float Bs[64][LDB];   // [k][m]
  const float* yb = y + (size_t)b * NN * Cc;
  int t = threadIdx.x;
  int tx = t & 15, ty = t >> 4;
  float4 acc[8];
#pragma unroll
  for (int i = 0; i < 8; ++i) acc[i] = {0.f, 0.f, 0.f, 0.f};
  for (int k0 = 0; k0 < Cc; k0 += 64) {
    __syncthreads();
#pragma unroll
    for (int i = 0; i < 8; ++i) {                 // A rows n0..n0+127, transpose
      int fi = i * 256 + t;
      int r = fi >> 4, j = fi & 15;
      float4 av = *(const float4*)&yb[(size_t)(n0 + r) * Cc + k0 + j * 4];
      As[j * 4 + 0][r] = av.x; As[j * 4 + 1][r] = av.y;
      As[j * 4 + 2][r] = av.z; As[j * 4 + 3][r] = av.w;
    }
#pragma unroll
    for (int i = 0; i < 4; ++i) {                 // B rows m0..m0+63, transpose
      int fi = i * 256 + t;
      int m = fi >> 4, j = fi & 15;
      float4 bv = *(const float4*)&yb[(size_t)(m0 + m) * Cc + k0 + j * 4];
      Bs[j * 4 + 0][m] = bv.x; Bs[j * 4 + 1][m] = bv.y;
      Bs[j * 4 + 2][m] = bv.z; Bs[j * 4 + 3][m] = bv.w;
    }
    __syncthreads();
#pragma unroll 8
    for (int k = 0; k < 64; ++k) {
      float4 a0 = *(const float4*)&As[k][ty * 4];
      float4 a1 = *(const float4*)&As[k][64 + ty * 4];
      float4 b  = *(const float4*)&Bs[k][tx * 4];
      FMA_ROW(acc[0], a0.x, b)
      FMA_ROW(acc[1], a0.y, b)
      FMA_ROW(acc[2], a0.z, b)
      FMA_ROW(acc[3], a0.w, b)
      FMA_ROW(acc[4], a1.x, b)
      FMA_ROW(acc[5], a1.y, b)
      FMA_ROW(acc[6], a1.z, b)
      FMA_ROW(acc[7], a1.w, b)
    }
  }
#pragma unroll
  for (int ii = 0; ii < 8; ++ii) {
    int n = n0 + ((ii < 4) ? (ty * 4 + ii) : (64 + ty * 4 + ii - 4));
    float sn = sq[b * NN + n];
    int mbase = m0 + tx * 4;
    float av[4] = {acc[ii].x, acc[ii].y, acc[ii].z, acc[ii].w};
    float4 o;
    o.x = sn + sq[b * NN + mbase + 0] - 2.f * av[0];
    o.y = sn + sq[b * NN + mbase + 1] - 2.f * av[1];
    o.z = sn + sq[b * NN + mbase + 2] - 2.f * av[2];
    o.w = sn + sq[b * NN + mbase + 3] - 2.f * av[3];
    *(float4*)&dist[((size_t)b * NN + n) * NN + mbase] = o;
  }
}

// ---------------------------------------------------------------- top-16 smallest per row (unchanged)
__global__ __launch_bounds__(64) void k_topk(const float* __restrict__ dist,
                                             int* __restrict__ idx) {
  int bn = blockIdx.x;
  int lane = threadIdx.x;
  const float4* dp = (const float4*)(dist + (size_t)bn * NN);
  float dv[16];
#pragma unroll
  for (int q = 0; q < 4; ++q) {
    float4 v = dp[lane + 64 * q];
    dv[q * 4 + 0] = v.x; dv[q * 4 + 1] = v.y;
    dv[q * 4 + 2] = v.z; dv[q * 4 + 3] = v.w;
  }
  for (int sel = 0; sel < KN; ++sel) {
    float bv = INFINITY;
    int bi = 0x7fffffff;
#pragma unroll
    for (int q = 0; q < 4; ++q)
#pragma unroll
      for (int j = 0; j < 4; ++j) {
        int m = (lane + 64 * q) * 4 + j;
        float v = dv[q * 4 + j];
        if (v < bv || (v == bv && m < bi)) { bv = v; bi = m; }
      }
#pragma unroll
    for (int off = 32; off; off >>= 1) {
      float ov = __shfl_xor(bv, off);
      int oi   = __shfl_xor(bi, off);
      if (ov < bv || (ov == bv && oi < bi)) { bv = ov; bi = oi; }
    }
    if (lane == 0) idx[bn * KN + sel] = bi;
#pragma unroll
    for (int q = 0; q < 4; ++q)
#pragma unroll
      for (int j = 0; j < 4; ++j)
        if ((lane + 64 * q) * 4 + j == bi) dv[q * 4 + j] = INFINITY;
  }
}

// ---------------------------------------------------------------- GAT aggregate + BN + GELU (unchanged from R2)
__global__ __launch_bounds__(128, 4) void k_gat(
    const float* __restrict__ h, const float* __restrict__ asrc,
    const float* __restrict__ adst, const int* __restrict__ idx,
    const float* __restrict__ bg, const float* __restrict__ bng,
    float* __restrict__ g) {
  int bid = blockIdx.x;
  int bn = (bid & 7) * (Bb * NN / 8) + (bid >> 3);   // bijective XCD swizzle
  int b = bn / NN;
  __shared__ int nb[KN];
  __shared__ float attn[KN][NH];
  int t = threadIdx.x;
  if (t < KN) nb[t] = idx[bn * KN + t];
  __syncthreads();
  if (t < KN * NH) {
    int k = t % KN, hd = t / KN;
    float e = asrc[((size_t)b * NN + nb[k]) * NH + hd] +
              adst[(size_t)bn * NH + hd];
    e = (e >= 0.f) ? e : 0.2f * e;
    attn[k][hd] = e;
  }
  __syncthreads();
  if (t < NH) {
    float mx = -INFINITY;
    for (int k = 0; k < KN; ++k) mx = fmaxf(mx, attn[k][t]);
    float s = 0.f;
    for (int k = 0; k < KN; ++k) {
      float ev = expf(attn[k][t] - mx);
      attn[k][t] = ev;
      s += ev;
    }
    float inv = 1.f / s;
    for (int k = 0; k < KN; ++k) attn[k][t] *= inv;
  }
  __syncthreads();
  if (t < 96) {
    int d = t * 4;
    float4 acc = {0.f, 0.f, 0.f, 0.f};
#pragma unroll 4
    for (int k = 0; k < KN; ++k) {
      const float* hp = h + ((size_t)b * NN + nb[k]) * FF + d;
      float4 aw = *(const float4*)&attn[k][0];
      float4 h0 = *(const float4*)&hp[0];
      float4 h1 = *(const float4*)&hp[HD];
      float4 h2 = *(const float4*)&hp[2 * HD];
      float4 h3 = *(const float4*)&hp[3 * HD];
      acc.x = fmaf(aw.x, h0.x, acc.x); acc.x = fmaf(aw.y, h1.x, acc.x);
      acc.x = fmaf(aw.z, h2.x, acc.x); acc.x = fmaf(aw.w, h3.x, acc.x);
      acc.y = fmaf(aw.x, h0.y, acc.y); acc.y = fmaf(aw.y, h1.y, acc.y);
      acc.y = fmaf(aw.z, h2.y, acc.y); acc.y = fmaf(aw.w, h3.y, acc.y);
      acc.z = fmaf(aw.x, h0.z, acc.z); acc.z = fmaf(aw.y, h1.z, acc.z);
      acc.z = fmaf(aw.z, h2.z, acc.z); acc.z = fmaf(aw.w, h3.z, acc.z);
      acc.w = fmaf(aw.x, h0.w, acc.w); acc.w = fmaf(aw.y, h1.w, acc.w);
      acc.w = fmaf(aw.z, h2.w, acc.w); acc.w = fmaf(aw.w, h3.w, acc.w);
    }
    float o[4] = {acc.x, acc.y, acc.z, acc.w};
    float4 r;
    float* rp = (float*)&r;
#pragma unroll
    for (int j = 0; j < 4; ++j) {
      int dd = d + j;
      float val = o[j] * 0.25f + bg[dd];
      float sc = bng[dd] / sqrtf(bng[3 * HD + dd] + BN_EPS);
      val = (val - bng[2 * HD + dd]) * sc + bng[HD + dd];
      val = 0.5f * val * (1.f + erff(val * 0.7071067811865475f));
      rp[j] = val;
    }
    *(float4*)&g[(size_t)bn * HD + d] = r;
  }
}

// ---------------------------------------------------------------- fc2 + BN + residual + transpose (padded LDS)
__global__ __launch_bounds__(256) void k_fc2(
    const float* __restrict__ g, const float* __restrict__ W2,
    const float* __restrict__ b2, const float* __restrict__ bn2,
    const float* __restrict__ x, float* __restrict__ out) {
  int nt = blockIdx.x, ct = blockIdx.y, b = blockIdx.z;
  int n0 = nt * 64, c0 = ct * 64;
  __shared__ float As[64][LDB];   // [k][n]
  __shared__ float Bs[64][LDB];   // [k][c]
  int t = threadIdx.x;
  int tx = t & 15, ty = t >> 4;
  float4 acc[4];
#pragma unroll
  for (int i = 0; i < 4; ++i) acc[i] = {0.f, 0.f, 0.f, 0.f};
  for (int k0 = 0; k0 < HD; k0 += 64) {
    __syncthreads();
#pragma unroll
    for (int i = 0; i < 4; ++i) {
      int fi = i * 256 + t;
      int r = fi >> 4, q = fi & 15;
      // A: g[n0+r][k0+q*4] -> transpose
      float4 av = *(const float4*)&g[((size_t)b * NN + n0 + r) * HD + k0 + q * 4];
      As[q * 4 + 0][r] = av.x; As[q * 4 + 1][r] = av.y;
      As[q * 4 + 2][r] = av.z; As[q * 4 + 3][r] = av.w;
      // B: W2[c0+r][k0+q*4] -> transpose
      float4 bv = *(const float4*)&W2[(size_t)(c0 + r) * HD + k0 + q * 4];
      Bs[q * 4 + 0][r] = bv.x; Bs[q * 4 + 1][r] = bv.y;
      Bs[q * 4 + 2][r] = bv.z; Bs[q * 4 + 3][r] = bv.w;
    }
    __syncthreads();
#pragma unroll 8
    for (int k = 0; k < 64; ++k) {
      float4 a = *(const float4*)&As[k][ty * 4];
      float4 bv = *(const float4*)&Bs[k][tx * 4];
      FMA_ROW(acc[0], a.x, bv)
      FMA_ROW(acc[1], a.y, bv)
      FMA_ROW(acc[2], a.z, bv)
      FMA_ROW(acc[3], a.w, bv)
    }
  }
  float accm[4][4] = {
      {acc[0].x, acc[0].y, acc[0].z, acc[0].w},
      {acc[1].x, acc[1].y, acc[1].z, acc[1].w},
      {acc[2].x, acc[2].y, acc[2].z, acc[2].w},
      {acc[3].x, acc[3].y, acc[3].z, acc[3].w}};
#pragma unroll
  for (int jj = 0; jj < 4; ++jj) {
    int c = c0 + tx * 4 + jj;
    float s  = bn2[c] / sqrtf(bn2[3 * Cc + c] + BN_EPS);
    float mm = bn2[2 * Cc + c];
    float be = bn2[Cc + c];
    float bias = b2[c];
    float4 res = *(const float4*)&x[((size_t)b * Cc + c) * NN + n0 + ty * 4];
    float4 o;
    o.x = (accm[0][jj] + bias - mm) * s + be + res.x;
    o.y = (accm[1][jj] + bias - mm) * s + be + res.y;
    o.z = (accm[2][jj] + bias - mm) * s + be + res.z;
    o.w = (accm[3][jj] + bias - mm) * s + be + res.w;
    *(float4*)&out[((size_t)b * Cc + c) * NN + n0 + ty * 4] = o;
  }
}

extern "C" void kernel_launch(void* const* d_in, const int* in_sizes, int n_in,
                              void* d_out, int out_size, void* d_ws, size_t ws_size,
                              hipStream_t stream) {
  const float* x       = (const float*)d_in[0];
  const float* W1      = (const float*)d_in[1];
  const float* b1      = (const float*)d_in[2];
  const float* bn1     = (const float*)d_in[3];
  const float* Wg      = (const float*)d_in[4];
  const float* att_src = (const float*)d_in[5];
  const float* att_dst = (const float*)d_in[6];
  const float* bg      = (const float*)d_in[7];
  const float* bng     = (const float*)d_in[8];
  const float* W2      = (const float*)d_in[9];
  const float* b2      = (const float*)d_in[10];
  const float* bn2     = (const float*)d_in[11];
  float* out = (float*)d_out;

  float* ws   = (float*)d_ws;
  float* y    = ws;                        // 786432
  float* h    = y + 786432;                // 6291456
  float* sq   = h + 6291456;               // 4096
  float* asrc = sq + 4096;                 // 16384
  float* adst = asrc + 16384;              // 16384
  float* dist = adst + 16384;              // 4194304
  float* g    = dist;                      // 1572864 (reuse; dist dead after topk)
  int*   idx  = (int*)(dist + 4194304);    // 65536 ints

  k_fc1<<<dim3(16, 3, 4), 256, 0, stream>>>(x, W1, b1, bn1, y);
  k_sq<<<Bb * NN, 64, 0, stream>>>(y, sq);
  k_hgemm<<<dim3(32, 24), 256, 0, stream>>>(y, Wg, h);
  k_attn_coef<<<Bb * NN, 256, 0, stream>>>(h, att_src, att_dst, asrc, adst);
  k_dist<<<dim3(16, 8, 4), 256, 0, stream>>>(y, sq, dist);
  k_topk<<<Bb * NN, 64, 0, stream>>>(dist, idx);
  k_gat<<<Bb * NN, 128, 0, stream>>>(h, asrc, adst, idx, bg, bng, g);
  k_fc2<<<dim3(16, 3, 4), 256, 0, stream>>>(g, W2, b2, bn2, x, out);
}

// Round 7
// 178.233 us; speedup vs baseline: 1.0761x; 1.0087x over previous
//
#include <hip/hip_runtime.h>
#include <math.h>

#define Bb 4
#define Cc 192
#define NN 1024
#define HD 384
#define NH 4
#define FF 1536   // NH*HD
#define KN 16
#define BN_EPS 1e-5f

// one row of register-tile FMAs: acc.{x,y,z,w} += av * b.{x,y,z,w}
#define FMA_ROW(ACC, AV, B) \
  ACC.x = fmaf(AV, B.x, ACC.x); ACC.y = fmaf(AV, B.y, ACC.y); \
  ACC.z = fmaf(AV, B.z, ACC.z); ACC.w = fmaf(AV, B.w, ACC.w);

// ---------------------------------------------------------------- generic 32x32 tiled transpose
// in: R x C (row-major) -> out: C x R. blockIdx.z = batch (stride R*C). R,C % 32 == 0.
__global__ __launch_bounds__(256) void k_tr(const float* __restrict__ in,
                                            float* __restrict__ out,
                                            int R, int C) {
  __shared__ float tile[32][33];
  int c0 = blockIdx.x * 32, r0 = blockIdx.y * 32;
  const float* ip = in + (size_t)blockIdx.z * R * C;
  float* op = out + (size_t)blockIdx.z * R * C;
  int tx = threadIdx.x & 31, ty = threadIdx.x >> 5;
#pragma unroll
  for (int i = 0; i < 4; ++i) {
    int r = ty + i * 8;
    tile[r][tx] = ip[(size_t)(r0 + r) * C + c0 + tx];
  }
  __syncthreads();
#pragma unroll
  for (int i = 0; i < 4; ++i) {
    int r = ty + i * 8;   // row within output tile (c-dim)
    op[(size_t)(c0 + r) * R + r0 + tx] = tile[tx][r];
  }
}

// ---------------------------------------------------------------- fc1 + BN
// y[b,n,c] = BN1( sum_k x[b,k,n]*W1T[k,c] + b1[c] ); both operands k-major -> direct stage.
__global__ __launch_bounds__(256) void k_fc1(
    const float* __restrict__ x, const float* __restrict__ W1T,
    const float* __restrict__ b1, const float* __restrict__ bn1,
    float* __restrict__ y) {
  int nt = blockIdx.x, ct = blockIdx.y, b = blockIdx.z;
  int n0 = nt * 64, ct64 = ct * 64;
  __shared__ float As[64][64];   // [k][n]
  __shared__ float Bs[64][64];   // [k][c]
  int t = threadIdx.x;
  int tx = t & 15, ty = t >> 4;
  float4 acc[4];
#pragma unroll
  for (int i = 0; i < 4; ++i) acc[i] = {0.f, 0.f, 0.f, 0.f};
  for (int k0 = 0; k0 < Cc; k0 += 64) {
    __syncthreads();
#pragma unroll
    for (int i = 0; i < 4; ++i) {
      int fi = i * 256 + t;
      int r = fi >> 4, q = fi & 15;
      *(float4*)&As[r][q * 4] =
          *(const float4*)&x[((size_t)b * Cc + k0 + r) * NN + n0 + q * 4];
      *(float4*)&Bs[r][q * 4] =
          *(const float4*)&W1T[(size_t)(k0 + r) * Cc + ct64 + q * 4];
    }
    __syncthreads();
#pragma unroll 8
    for (int k = 0; k < 64; ++k) {
      float4 a = *(const float4*)&As[k][ty * 4];
      float4 bv = *(const float4*)&Bs[k][tx * 4];
      FMA_ROW(acc[0], a.x, bv)
      FMA_ROW(acc[1], a.y, bv)
      FMA_ROW(acc[2], a.z, bv)
      FMA_ROW(acc[3], a.w, bv)
    }
  }
  float s[4], mm[4], be[4], bias[4];
#pragma unroll
  for (int jj = 0; jj < 4; ++jj) {
    int c = ct64 + tx * 4 + jj;
    s[jj]    = bn1[c] / sqrtf(bn1[3 * Cc + c] + BN_EPS);
    mm[jj]   = bn1[2 * Cc + c];
    be[jj]   = bn1[Cc + c];
    bias[jj] = b1[c];
  }
  float accm[4][4] = {
      {acc[0].x, acc[0].y, acc[0].z, acc[0].w},
      {acc[1].x, acc[1].y, acc[1].z, acc[1].w},
      {acc[2].x, acc[2].y, acc[2].z, acc[2].w},
      {acc[3].x, acc[3].y, acc[3].z, acc[3].w}};
#pragma unroll
  for (int ii = 0; ii < 4; ++ii) {
    int n = n0 + ty * 4 + ii;
    float4 o;
    o.x = (accm[ii][0] + bias[0] - mm[0]) * s[0] + be[0];
    o.y = (accm[ii][1] + bias[1] - mm[1]) * s[1] + be[1];
    o.z = (accm[ii][2] + bias[2] - mm[2]) * s[2] + be[2];
    o.w = (accm[ii][3] + bias[3] - mm[3]) * s[3] + be[3];
    *(float4*)&y[((size_t)b * NN + n) * Cc + ct64 + tx * 4] = o;
  }
}

// ---------------------------------------------------------------- row sums of y^2 (unchanged)
__global__ __launch_bounds__(64) void k_sq(const float* __restrict__ y,
                                           float* __restrict__ sq) {
  int bn = blockIdx.x;
  int lane = threadIdx.x;
  const float* yp = y + (size_t)bn * Cc;
  float s = 0.f;
  for (int k = lane; k < Cc; k += 64) { float v = yp[k]; s = fmaf(v, v, s); }
#pragma unroll
  for (int off = 32; off; off >>= 1) s += __shfl_down(s, off);
  if (lane == 0) sq[bn] = s;
}

// ---------------------------------------------------------------- h = y @ Wg  (128x64, 8x4/thread, direct stage from yT)
__global__ __launch_bounds__(256) void k_hgemm(const float* __restrict__ yT,
                                               const float* __restrict__ Wg,
                                               float* __restrict__ h) {
  int r0 = blockIdx.x * 128, c0 = blockIdx.y * 64;
  int b = r0 >> 10, nb = r0 & 1023;
  __shared__ float As[64][128];   // [k][row] 32KB
  __shared__ float Bs[64][64];    // [k][col] 16KB
  int t = threadIdx.x;
  int tx = t & 15, ty = t >> 4;
  float4 acc[8];
#pragma unroll
  for (int i = 0; i < 8; ++i) acc[i] = {0.f, 0.f, 0.f, 0.f};
  for (int k0 = 0; k0 < Cc; k0 += 64) {
    __syncthreads();
#pragma unroll
    for (int i = 0; i < 8; ++i) {                 // A: 64k x 128row direct from yT
      int fi = i * 256 + t;
      int kk = fi >> 5, n4 = fi & 31;
      *(float4*)&As[kk][n4 * 4] =
          *(const float4*)&yT[((size_t)b * Cc + k0 + kk) * NN + nb + n4 * 4];
    }
#pragma unroll
    for (int i = 0; i < 4; ++i) {                 // B: 64k x 64c direct from Wg
      int fi = i * 256 + t;
      int kk = fi >> 4, c4 = fi & 15;
      *(float4*)&Bs[kk][c4 * 4] =
          *(const float4*)&Wg[(size_t)(k0 + kk) * FF + c0 + c4 * 4];
    }
    __syncthreads();
#pragma unroll 8
    for (int k = 0; k < 64; ++k) {
      float4 a0 = *(const float4*)&As[k][ty * 4];
      float4 a1 = *(const float4*)&As[k][64 + ty * 4];
      float4 b4 = *(const float4*)&Bs[k][tx * 4];
      FMA_ROW(acc[0], a0.x, b4)
      FMA_ROW(acc[1], a0.y, b4)
      FMA_ROW(acc[2], a0.z, b4)
      FMA_ROW(acc[3], a0.w, b4)
      FMA_ROW(acc[4], a1.x, b4)
      FMA_ROW(acc[5], a1.y, b4)
      FMA_ROW(acc[6], a1.z, b4)
      FMA_ROW(acc[7], a1.w, b4)
    }
  }
#pragma unroll
  for (int ii = 0; ii < 8; ++ii) {
    int r = r0 + ((ii < 4) ? (ty * 4 + ii) : (64 + ty * 4 + ii - 4));
    *(float4*)&h[(size_t)r * FF + c0 + tx * 4] = acc[ii];
  }
}

// ---------------------------------------------------------------- a_src / a_dst (unchanged)
__global__ __launch_bounds__(256) void k_attn_coef(
    const float* __restrict__ h, const float* __restrict__ att_src,
    const float* __restrict__ att_dst, float* __restrict__ asrc,
    float* __restrict__ adst) {
  int bn = blockIdx.x;
  int head = threadIdx.x / 64, lane = threadIdx.x % 64;
  const float* hp = h + (size_t)bn * FF + head * HD;
  const float* as = att_src + head * HD;
  const float* ad = att_dst + head * HD;
  float s1 = 0.f, s2 = 0.f;
  for (int d = lane; d < HD; d += 64) {
    float v = hp[d];
    s1 = fmaf(v, as[d], s1);
    s2 = fmaf(v, ad[d], s2);
  }
#pragma unroll
  for (int off = 32; off; off >>= 1) {
    s1 += __shfl_down(s1, off);
    s2 += __shfl_down(s2, off);
  }
  if (lane == 0) {
    asrc[bn * NH + head] = s1;
    adst[bn * NH + head] = s2;
  }
}

// ---------------------------------------------------------------- pairwise distances (128x64, direct stage from yT)
__global__ __launch_bounds__(256) void k_dist(const float* __restrict__ yT,
                                              const float* __restrict__ sq,
                                              float* __restrict__ dist) {
  int b = blockIdx.z;
  int n0 = blockIdx.y * 128, m0 = blockIdx.x * 64;
  __shared__ float As[64][128];   // [k][n]
  __shared__ float Bs[64][64];    // [k][m]
  const float* ytb = yT + (size_t)b * Cc * NN;
  int t = threadIdx.x;
  int tx = t & 15, ty = t >> 4;
  float4 acc[8];
#pragma unroll
  for (int i = 0; i < 8; ++i) acc[i] = {0.f, 0.f, 0.f, 0.f};
  for (int k0 = 0; k0 < Cc; k0 += 64) {
    __syncthreads();
#pragma unroll
    for (int i = 0; i < 8; ++i) {                 // A: cols n0..n0+127
      int fi = i * 256 + t;
      int kk = fi >> 5, n4 = fi & 31;
      *(float4*)&As[kk][n4 * 4] =
          *(const float4*)&ytb[(size_t)(k0 + kk) * NN + n0 + n4 * 4];
    }
#pragma unroll
    for (int i = 0; i < 4; ++i) {                 // B: cols m0..m0+63
      int fi = i * 256 + t;
      int kk = fi >> 4, m4 = fi & 15;
      *(float4*)&Bs[kk][m4 * 4] =
          *(const float4*)&ytb[(size_t)(k0 + kk) * NN + m0 + m4 * 4];
    }
    __syncthreads();
#pragma unroll 8
    for (int k = 0; k < 64; ++k) {
      float4 a0 = *(const float4*)&As[k][ty * 4];
      float4 a1 = *(const float4*)&As[k][64 + ty * 4];
      float4 b4 = *(const float4*)&Bs[k][tx * 4];
      FMA_ROW(acc[0], a0.x, b4)
      FMA_ROW(acc[1], a0.y, b4)
      FMA_ROW(acc[2], a0.z, b4)
      FMA_ROW(acc[3], a0.w, b4)
      FMA_ROW(acc[4], a1.x, b4)
      FMA_ROW(acc[5], a1.y, b4)
      FMA_ROW(acc[6], a1.z, b4)
      FMA_ROW(acc[7], a1.w, b4)
    }
  }
#pragma unroll
  for (int ii = 0; ii < 8; ++ii) {
    int n = n0 + ((ii < 4) ? (ty * 4 + ii) : (64 + ty * 4 + ii - 4));
    float sn = sq[b * NN + n];
    int mbase = m0 + tx * 4;
    float av[4] = {acc[ii].x, acc[ii].y, acc[ii].z, acc[ii].w};
    float4 o;
    o.x = sn + sq[b * NN + mbase + 0] - 2.f * av[0];
    o.y = sn + sq[b * NN + mbase + 1] - 2.f * av[1];
    o.z = sn + sq[b * NN + mbase + 2] - 2.f * av[2];
    o.w = sn + sq[b * NN + mbase + 3] - 2.f * av[3];
    *(float4*)&dist[((size_t)b * NN + n) * NN + mbase] = o;
  }
}

// ---------------------------------------------------------------- top-16 smallest per row (unchanged)
__global__ __launch_bounds__(64) void k_topk(const float* __restrict__ dist,
                                             int* __restrict__ idx) {
  int bn = blockIdx.x;
  int lane = threadIdx.x;
  const float4* dp = (const float4*)(dist + (size_t)bn * NN);
  float dv[16];
#pragma unroll
  for (int q = 0; q < 4; ++q) {
    float4 v = dp[lane + 64 * q];
    dv[q * 4 + 0] = v.x; dv[q * 4 + 1] = v.y;
    dv[q * 4 + 2] = v.z; dv[q * 4 + 3] = v.w;
  }
  for (int sel = 0; sel < KN; ++sel) {
    float bv = INFINITY;
    int bi = 0x7fffffff;
#pragma unroll
    for (int q = 0; q < 4; ++q)
#pragma unroll
      for (int j = 0; j < 4; ++j) {
        int m = (lane + 64 * q) * 4 + j;
        float v = dv[q * 4 + j];
        if (v < bv || (v == bv && m < bi)) { bv = v; bi = m; }
      }
#pragma unroll
    for (int off = 32; off; off >>= 1) {
      float ov = __shfl_xor(bv, off);
      int oi   = __shfl_xor(bi, off);
      if (ov < bv || (ov == bv && oi < bi)) { bv = ov; bi = oi; }
    }
    if (lane == 0) idx[bn * KN + sel] = bi;
#pragma unroll
    for (int q = 0; q < 4; ++q)
#pragma unroll
      for (int j = 0; j < 4; ++j)
        if ((lane + 64 * q) * 4 + j == bi) dv[q * 4 + j] = INFINITY;
  }
}

// ---------------------------------------------------------------- GAT aggregate + BN + GELU (unchanged)
__global__ __launch_bounds__(128, 4) void k_gat(
    const float* __restrict__ h, const float* __restrict__ asrc,
    const float* __restrict__ adst, const int* __restrict__ idx,
    const float* __restrict__ bg, const float* __restrict__ bng,
    float* __restrict__ g) {
  int bid = blockIdx.x;
  int bn = (bid & 7) * (Bb * NN / 8) + (bid >> 3);   // bijective XCD swizzle
  int b = bn / NN;
  __shared__ int nb[KN];
  __shared__ float attn[KN][NH];
  int t = threadIdx.x;
  if (t < KN) nb[t] = idx[bn * KN + t];
  __syncthreads();
  if (t < KN * NH) {
    int k = t % KN, hd = t / KN;
    float e = asrc[((size_t)b * NN + nb[k]) * NH + hd] +
              adst[(size_t)bn * NH + hd];
    e = (e >= 0.f) ? e : 0.2f * e;
    attn[k][hd] = e;
  }
  __syncthreads();
  if (t < NH) {
    float mx = -INFINITY;
    for (int k = 0; k < KN; ++k) mx = fmaxf(mx, attn[k][t]);
    float s = 0.f;
    for (int k = 0; k < KN; ++k) {
      float ev = expf(attn[k][t] - mx);
      attn[k][t] = ev;
      s += ev;
    }
    float inv = 1.f / s;
    for (int k = 0; k < KN; ++k) attn[k][t] *= inv;
  }
  __syncthreads();
  if (t < 96) {
    int d = t * 4;
    float4 acc = {0.f, 0.f, 0.f, 0.f};
#pragma unroll 4
    for (int k = 0; k < KN; ++k) {
      const float* hp = h + ((size_t)b * NN + nb[k]) * FF + d;
      float4 aw = *(const float4*)&attn[k][0];
      float4 h0 = *(const float4*)&hp[0];
      float4 h1 = *(const float4*)&hp[HD];
      float4 h2 = *(const float4*)&hp[2 * HD];
      float4 h3 = *(const float4*)&hp[3 * HD];
      acc.x = fmaf(aw.x, h0.x, acc.x); acc.x = fmaf(aw.y, h1.x, acc.x);
      acc.x = fmaf(aw.z, h2.x, acc.x); acc.x = fmaf(aw.w, h3.x, acc.x);
      acc.y = fmaf(aw.x, h0.y, acc.y); acc.y = fmaf(aw.y, h1.y, acc.y);
      acc.y = fmaf(aw.z, h2.y, acc.y); acc.y = fmaf(aw.w, h3.y, acc.y);
      acc.z = fmaf(aw.x, h0.z, acc.z); acc.z = fmaf(aw.y, h1.z, acc.z);
      acc.z = fmaf(aw.z, h2.z, acc.z); acc.z = fmaf(aw.w, h3.z, acc.z);
      acc.w = fmaf(aw.x, h0.w, acc.w); acc.w = fmaf(aw.y, h1.w, acc.w);
      acc.w = fmaf(aw.z, h2.w, acc.w); acc.w = fmaf(aw.w, h3.w, acc.w);
    }
    float o[4] = {acc.x, acc.y, acc.z, acc.w};
    float4 r;
    float* rp = (float*)&r;
#pragma unroll
    for (int j = 0; j < 4; ++j) {
      int dd = d + j;
      float val = o[j] * 0.25f + bg[dd];
      float sc = bng[dd] / sqrtf(bng[3 * HD + dd] + BN_EPS);
      val = (val - bng[2 * HD + dd]) * sc + bng[HD + dd];
      val = 0.5f * val * (1.f + erff(val * 0.7071067811865475f));
      rp[j] = val;
    }
    *(float4*)&g[(size_t)bn * HD + d] = r;
  }
}

// ---------------------------------------------------------------- fc2 + BN + residual + transpose-out (direct stage from gT/W2T)
__global__ __launch_bounds__(256) void k_fc2(
    const float* __restrict__ gT, const float* __restrict__ W2T,
    const float* __restrict__ b2, const float* __restrict__ bn2,
    const float* __restrict__ x, float* __restrict__ out) {
  int nt = blockIdx.x, ct = blockIdx.y, b = blockIdx.z;
  int n0 = nt * 64, c0 = ct * 64;
  __shared__ float As[64][64];   // [k][n]
  __shared__ float Bs[64][64];   // [k][c]
  int t = threadIdx.x;
  int tx = t & 15, ty = t >> 4;
  float4 acc[4];
#pragma unroll
  for (int i = 0; i < 4; ++i) acc[i] = {0.f, 0.f, 0.f, 0.f};
  for (int k0 = 0; k0 < HD; k0 += 64) {
    __syncthreads();
#pragma unroll
    for (int i = 0; i < 4; ++i) {
      int fi = i * 256 + t;
      int r = fi >> 4, q = fi & 15;
      *(float4*)&As[r][q * 4] =
          *(const float4*)&gT[((size_t)b * HD + k0 + r) * NN + n0 + q * 4];
      *(float4*)&Bs[r][q * 4] =
          *(const float4*)&W2T[(size_t)(k0 + r) * Cc + c0 + q * 4];
    }
    __syncthreads();
#pragma unroll 8
    for (int k = 0; k < 64; ++k) {
      float4 a = *(const float4*)&As[k][ty * 4];
      float4 bv = *(const float4*)&Bs[k][tx * 4];
      FMA_ROW(acc[0], a.x, bv)
      FMA_ROW(acc[1], a.y, bv)
      FMA_ROW(acc[2], a.z, bv)
      FMA_ROW(acc[3], a.w, bv)
    }
  }
  float accm[4][4] = {
      {acc[0].x, acc[0].y, acc[0].z, acc[0].w},
      {acc[1].x, acc[1].y, acc[1].z, acc[1].w},
      {acc[2].x, acc[2].y, acc[2].z, acc[2].w},
      {acc[3].x, acc[3].y, acc[3].z, acc[3].w}};
#pragma unroll
  for (int jj = 0; jj < 4; ++jj) {
    int c = c0 + tx * 4 + jj;
    float s  = bn2[c] / sqrtf(bn2[3 * Cc + c] + BN_EPS);
    float mm = bn2[2 * Cc + c];
    float be = bn2[Cc + c];
    float bias = b2[c];
    float4 res = *(const float4*)&x[((size_t)b * Cc + c) * NN + n0 + ty * 4];
    float4 o;
    o.x = (accm[0][jj] + bias - mm) * s + be + res.x;
    o.y = (accm[1][jj] + bias - mm) * s + be + res.y;
    o.z = (accm[2][jj] + bias - mm) * s + be + res.z;
    o.w = (accm[3][jj] + bias - mm) * s + be + res.w;
    *(float4*)&out[((size_t)b * Cc + c) * NN + n0 + ty * 4] = o;
  }
}

extern "C" void kernel_launch(void* const* d_in, const int* in_sizes, int n_in,
                              void* d_out, int out_size, void* d_ws, size_t ws_size,
                              hipStream_t stream) {
  const float* x       = (const float*)d_in[0];
  const float* W1      = (const float*)d_in[1];
  const float* b1      = (const float*)d_in[2];
  const float* bn1     = (const float*)d_in[3];
  const float* Wg      = (const float*)d_in[4];
  const float* att_src = (const float*)d_in[5];
  const float* att_dst = (const float*)d_in[6];
  const float* bg      = (const float*)d_in[7];
  const float* bng     = (const float*)d_in[8];
  const float* W2      = (const float*)d_in[9];
  const float* b2      = (const float*)d_in[10];
  const float* bn2     = (const float*)d_in[11];
  float* out = (float*)d_out;

  float* ws   = (float*)d_ws;
  float* y    = ws;                        // 786432
  float* h    = y + 786432;                // 6291456
  float* sq   = h + 6291456;               // 4096
  float* asrc = sq + 4096;                 // 16384
  float* adst = asrc + 16384;              // 16384
  float* dist = adst + 16384;              // 4194304
  float* g    = dist;                      // 1572864 (reuse; dist dead after topk)
  int*   idx  = (int*)(dist + 4194304);    // 65536 ints
  float* yT   = dist + 4194304 + 65536;    // 786432  [b][k][n]
  float* gT   = yT + 786432;               // 1572864 [b][d][n]
  float* W1T  = gT + 1572864;              // 36864   [k][c]
  float* W2T  = W1T + 36864;               // 73728   [k][c]

  k_tr<<<dim3(6, 6, 1), 256, 0, stream>>>(W1, W1T, Cc, Cc);
  k_tr<<<dim3(12, 6, 1), 256, 0, stream>>>(W2, W2T, Cc, HD);
  k_fc1<<<dim3(16, 3, 4), 256, 0, stream>>>(x, W1T, b1, bn1, y);
  k_tr<<<dim3(6, 32, 4), 256, 0, stream>>>(y, yT, NN, Cc);
  k_sq<<<Bb * NN, 64, 0, stream>>>(y, sq);
  k_hgemm<<<dim3(32, 24), 256, 0, stream>>>(yT, Wg, h);
  k_attn_coef<<<Bb * NN, 256, 0, stream>>>(h, att_src, att_dst, asrc, adst);
  k_dist<<<dim3(16, 8, 4), 256, 0, stream>>>(yT, sq, dist);
  k_topk<<<Bb * NN, 64, 0, stream>>>(dist, idx);
  k_gat<<<Bb * NN, 128, 0, stream>>>(h, asrc, adst, idx, bg, bng, g);
  k_tr<<<dim3(12, 32, 4), 256, 0, stream>>>(g, gT, NN, HD);
  k_fc2<<<dim3(16, 3, 4), 256, 0, stream>>>(gT, W2T, b2, bn2, x, out);
}

// Round 8
// 178.164 us; speedup vs baseline: 1.0765x; 1.0004x over previous
//
#include <hip/hip_runtime.h>
#include <math.h>

#define Bb 4
#define Cc 192
#define NN 1024
#define HD 384
#define NH 4
#define FF 1536   // NH*HD
#define KN 16
#define BN_EPS 1e-5f

// one row of register-tile FMAs: acc.{x,y,z,w} += av * b.{x,y,z,w}
#define FMA_ROW(ACC, AV, B) \
  ACC.x = fmaf(AV, B.x, ACC.x); ACC.y = fmaf(AV, B.y, ACC.y); \
  ACC.z = fmaf(AV, B.z, ACC.z); ACC.w = fmaf(AV, B.w, ACC.w);

// ---------------------------------------------------------------- generic 32x32 tiled transpose
// in: R x C (row-major) -> out: C x R. blockIdx.z = batch (stride R*C). R,C % 32 == 0.
__global__ __launch_bounds__(256) void k_tr(const float* __restrict__ in,
                                            float* __restrict__ out,
                                            int R, int C) {
  __shared__ float tile[32][33];
  int c0 = blockIdx.x * 32, r0 = blockIdx.y * 32;
  const float* ip = in + (size_t)blockIdx.z * R * C;
  float* op = out + (size_t)blockIdx.z * R * C;
  int tx = threadIdx.x & 31, ty = threadIdx.x >> 5;
#pragma unroll
  for (int i = 0; i < 4; ++i) {
    int r = ty + i * 8;
    tile[r][tx] = ip[(size_t)(r0 + r) * C + c0 + tx];
  }
  __syncthreads();
#pragma unroll
  for (int i = 0; i < 4; ++i) {
    int r = ty + i * 8;   // row within output tile (c-dim)
    op[(size_t)(c0 + r) * R + r0 + tx] = tile[tx][r];
  }
}

// ---------------------------------------------------------------- fc1 + BN
// y[b,n,c] = BN1( sum_k x[b,k,n]*W1T[k,c] + b1[c] ); both operands k-major -> direct stage.
__global__ __launch_bounds__(256) void k_fc1(
    const float* __restrict__ x, const float* __restrict__ W1T,
    const float* __restrict__ b1, const float* __restrict__ bn1,
    float* __restrict__ y) {
  int nt = blockIdx.x, ct = blockIdx.y, b = blockIdx.z;
  int n0 = nt * 64, ct64 = ct * 64;
  __shared__ float As[64][64];   // [k][n]
  __shared__ float Bs[64][64];   // [k][c]
  int t = threadIdx.x;
  int tx = t & 15, ty = t >> 4;
  float4 acc[4];
#pragma unroll
  for (int i = 0; i < 4; ++i) acc[i] = {0.f, 0.f, 0.f, 0.f};
  for (int k0 = 0; k0 < Cc; k0 += 64) {
    __syncthreads();
#pragma unroll
    for (int i = 0; i < 4; ++i) {
      int fi = i * 256 + t;
      int r = fi >> 4, q = fi & 15;
      *(float4*)&As[r][q * 4] =
          *(const float4*)&x[((size_t)b * Cc + k0 + r) * NN + n0 + q * 4];
      *(float4*)&Bs[r][q * 4] =
          *(const float4*)&W1T[(size_t)(k0 + r) * Cc + ct64 + q * 4];
    }
    __syncthreads();
#pragma unroll 8
    for (int k = 0; k < 64; ++k) {
      float4 a = *(const float4*)&As[k][ty * 4];
      float4 bv = *(const float4*)&Bs[k][tx * 4];
      FMA_ROW(acc[0], a.x, bv)
      FMA_ROW(acc[1], a.y, bv)
      FMA_ROW(acc[2], a.z, bv)
      FMA_ROW(acc[3], a.w, bv)
    }
  }
  float s[4], mm[4], be[4], bias[4];
#pragma unroll
  for (int jj = 0; jj < 4; ++jj) {
    int c = ct64 + tx * 4 + jj;
    s[jj]    = bn1[c] / sqrtf(bn1[3 * Cc + c] + BN_EPS);
    mm[jj]   = bn1[2 * Cc + c];
    be[jj]   = bn1[Cc + c];
    bias[jj] = b1[c];
  }
  float accm[4][4] = {
      {acc[0].x, acc[0].y, acc[0].z, acc[0].w},
      {acc[1].x, acc[1].y, acc[1].z, acc[1].w},
      {acc[2].x, acc[2].y, acc[2].z, acc[2].w},
      {acc[3].x, acc[3].y, acc[3].z, acc[3].w}};
#pragma unroll
  for (int ii = 0; ii < 4; ++ii) {
    int n = n0 + ty * 4 + ii;
    float4 o;
    o.x = (accm[ii][0] + bias[0] - mm[0]) * s[0] + be[0];
    o.y = (accm[ii][1] + bias[1] - mm[1]) * s[1] + be[1];
    o.z = (accm[ii][2] + bias[2] - mm[2]) * s[2] + be[2];
    o.w = (accm[ii][3] + bias[3] - mm[3]) * s[3] + be[3];
    *(float4*)&y[((size_t)b * NN + n) * Cc + ct64 + tx * 4] = o;
  }
}

// ---------------------------------------------------------------- row sums of y^2 (unchanged)
__global__ __launch_bounds__(64) void k_sq(const float* __restrict__ y,
                                           float* __restrict__ sq) {
  int bn = blockIdx.x;
  int lane = threadIdx.x;
  const float* yp = y + (size_t)bn * Cc;
  float s = 0.f;
  for (int k = lane; k < Cc; k += 64) { float v = yp[k]; s = fmaf(v, v, s); }
#pragma unroll
  for (int off = 32; off; off >>= 1) s += __shfl_down(s, off);
  if (lane == 0) sq[bn] = s;
}

// ---------------------------------------------------------------- h = y @ Wg  (128x64, 8x4/thread, direct stage from yT)
__global__ __launch_bounds__(256) void k_hgemm(const float* __restrict__ yT,
                                               const float* __restrict__ Wg,
                                               float* __restrict__ h) {
  int r0 = blockIdx.x * 128, c0 = blockIdx.y * 64;
  int b = r0 >> 10, nb = r0 & 1023;
  __shared__ float As[64][128];   // [k][row] 32KB
  __shared__ float Bs[64][64];    // [k][col] 16KB
  int t = threadIdx.x;
  int tx = t & 15, ty = t >> 4;
  float4 acc[8];
#pragma unroll
  for (int i = 0; i < 8; ++i) acc[i] = {0.f, 0.f, 0.f, 0.f};
  for (int k0 = 0; k0 < Cc; k0 += 64) {
    __syncthreads();
#pragma unroll
    for (int i = 0; i < 8; ++i) {                 // A: 64k x 128row direct from yT
      int fi = i * 256 + t;
      int kk = fi >> 5, n4 = fi & 31;
      *(float4*)&As[kk][n4 * 4] =
          *(const float4*)&yT[((size_t)b * Cc + k0 + kk) * NN + nb + n4 * 4];
    }
#pragma unroll
    for (int i = 0; i < 4; ++i) {                 // B: 64k x 64c direct from Wg
      int fi = i * 256 + t;
      int kk = fi >> 4, c4 = fi & 15;
      *(float4*)&Bs[kk][c4 * 4] =
          *(const float4*)&Wg[(size_t)(k0 + kk) * FF + c0 + c4 * 4];
    }
    __syncthreads();
#pragma unroll 8
    for (int k = 0; k < 64; ++k) {
      float4 a0 = *(const float4*)&As[k][ty * 4];
      float4 a1 = *(const float4*)&As[k][64 + ty * 4];
      float4 b4 = *(const float4*)&Bs[k][tx * 4];
      FMA_ROW(acc[0], a0.x, b4)
      FMA_ROW(acc[1], a0.y, b4)
      FMA_ROW(acc[2], a0.z, b4)
      FMA_ROW(acc[3], a0.w, b4)
      FMA_ROW(acc[4], a1.x, b4)
      FMA_ROW(acc[5], a1.y, b4)
      FMA_ROW(acc[6], a1.z, b4)
      FMA_ROW(acc[7], a1.w, b4)
    }
  }
#pragma unroll
  for (int ii = 0; ii < 8; ++ii) {
    int r = r0 + ((ii < 4) ? (ty * 4 + ii) : (64 + ty * 4 + ii - 4));
    *(float4*)&h[(size_t)r * FF + c0 + tx * 4] = acc[ii];
  }
}

// ---------------------------------------------------------------- a_src / a_dst (unchanged)
__global__ __launch_bounds__(256) void k_attn_coef(
    const float* __restrict__ h, const float* __restrict__ att_src,
    const float* __restrict__ att_dst, float* __restrict__ asrc,
    float* __restrict__ adst) {
  int bn = blockIdx.x;
  int head = threadIdx.x / 64, lane = threadIdx.x % 64;
  const float* hp = h + (size_t)bn * FF + head * HD;
  const float* as = att_src + head * HD;
  const float* ad = att_dst + head * HD;
  float s1 = 0.f, s2 = 0.f;
  for (int d = lane; d < HD; d += 64) {
    float v = hp[d];
    s1 = fmaf(v, as[d], s1);
    s2 = fmaf(v, ad[d], s2);
  }
#pragma unroll
  for (int off = 32; off; off >>= 1) {
    s1 += __shfl_down(s1, off);
    s2 += __shfl_down(s2, off);
  }
  if (lane == 0) {
    asrc[bn * NH + head] = s1;
    adst[bn * NH + head] = s2;
  }
}

// ---------------------------------------------------------------- pairwise distances (128x64, direct stage from yT)
__global__ __launch_bounds__(256) void k_dist(const float* __restrict__ yT,
                                              const float* __restrict__ sq,
                                              float* __restrict__ dist) {
  int b = blockIdx.z;
  int n0 = blockIdx.y * 128, m0 = blockIdx.x * 64;
  __shared__ float As[64][128];   // [k][n]
  __shared__ float Bs[64][64];    // [k][m]
  const float* ytb = yT + (size_t)b * Cc * NN;
  int t = threadIdx.x;
  int tx = t & 15, ty = t >> 4;
  float4 acc[8];
#pragma unroll
  for (int i = 0; i < 8; ++i) acc[i] = {0.f, 0.f, 0.f, 0.f};
  for (int k0 = 0; k0 < Cc; k0 += 64) {
    __syncthreads();
#pragma unroll
    for (int i = 0; i < 8; ++i) {                 // A: cols n0..n0+127
      int fi = i * 256 + t;
      int kk = fi >> 5, n4 = fi & 31;
      *(float4*)&As[kk][n4 * 4] =
          *(const float4*)&ytb[(size_t)(k0 + kk) * NN + n0 + n4 * 4];
    }
#pragma unroll
    for (int i = 0; i < 4; ++i) {                 // B: cols m0..m0+63
      int fi = i * 256 + t;
      int kk = fi >> 4, m4 = fi & 15;
      *(float4*)&Bs[kk][m4 * 4] =
          *(const float4*)&ytb[(size_t)(k0 + kk) * NN + m0 + m4 * 4];
    }
    __syncthreads();
#pragma unroll 8
    for (int k = 0; k < 64; ++k) {
      float4 a0 = *(const float4*)&As[k][ty * 4];
      float4 a1 = *(const float4*)&As[k][64 + ty * 4];
      float4 b4 = *(const float4*)&Bs[k][tx * 4];
      FMA_ROW(acc[0], a0.x, b4)
      FMA_ROW(acc[1], a0.y, b4)
      FMA_ROW(acc[2], a0.z, b4)
      FMA_ROW(acc[3], a0.w, b4)
      FMA_ROW(acc[4], a1.x, b4)
      FMA_ROW(acc[5], a1.y, b4)
      FMA_ROW(acc[6], a1.z, b4)
      FMA_ROW(acc[7], a1.w, b4)
    }
  }
#pragma unroll
  for (int ii = 0; ii < 8; ++ii) {
    int n = n0 + ((ii < 4) ? (ty * 4 + ii) : (64 + ty * 4 + ii - 4));
    float sn = sq[b * NN + n];
    int mbase = m0 + tx * 4;
    float av[4] = {acc[ii].x, acc[ii].y, acc[ii].z, acc[ii].w};
    float4 o;
    o.x = sn + sq[b * NN + mbase + 0] - 2.f * av[0];
    o.y = sn + sq[b * NN + mbase + 1] - 2.f * av[1];
    o.z = sn + sq[b * NN + mbase + 2] - 2.f * av[2];
    o.w = sn + sq[b * NN + mbase + 3] - 2.f * av[3];
    *(float4*)&dist[((size_t)b * NN + n) * NN + mbase] = o;
  }
}

// ---------------------------------------------------------------- top-16 smallest per row (unchanged)
__global__ __launch_bounds__(64) void k_topk(const float* __restrict__ dist,
                                             int* __restrict__ idx) {
  int bn = blockIdx.x;
  int lane = threadIdx.x;
  const float4* dp = (const float4*)(dist + (size_t)bn * NN);
  float dv[16];
#pragma unroll
  for (int q = 0; q < 4; ++q) {
    float4 v = dp[lane + 64 * q];
    dv[q * 4 + 0] = v.x; dv[q * 4 + 1] = v.y;
    dv[q * 4 + 2] = v.z; dv[q * 4 + 3] = v.w;
  }
  for (int sel = 0; sel < KN; ++sel) {
    float bv = INFINITY;
    int bi = 0x7fffffff;
#pragma unroll
    for (int q = 0; q < 4; ++q)
#pragma unroll
      for (int j = 0; j < 4; ++j) {
        int m = (lane + 64 * q) * 4 + j;
        float v = dv[q * 4 + j];
        if (v < bv || (v == bv && m < bi)) { bv = v; bi = m; }
      }
#pragma unroll
    for (int off = 32; off; off >>= 1) {
      float ov = __shfl_xor(bv, off);
      int oi   = __shfl_xor(bi, off);
      if (ov < bv || (ov == bv && oi < bi)) { bv = ov; bi = oi; }
    }
    if (lane == 0) idx[bn * KN + sel] = bi;
#pragma unroll
    for (int q = 0; q < 4; ++q)
#pragma unroll
      for (int j = 0; j < 4; ++j)
        if ((lane + 64 * q) * 4 + j == bi) dv[q * 4 + j] = INFINITY;
  }
}

// ---------------------------------------------------------------- GAT aggregate + BN + GELU (unchanged)
__global__ __launch_bounds__(128, 4) void k_gat(
    const float* __restrict__ h, const float* __restrict__ asrc,
    const float* __restrict__ adst, const int* __restrict__ idx,
    const float* __restrict__ bg, const float* __restrict__ bng,
    float* __restrict__ g) {
  int bid = blockIdx.x;
  int bn = (bid & 7) * (Bb * NN / 8) + (bid >> 3);   // bijective XCD swizzle
  int b = bn / NN;
  __shared__ int nb[KN];
  __shared__ float attn[KN][NH];
  int t = threadIdx.x;
  if (t < KN) nb[t] = idx[bn * KN + t];
  __syncthreads();
  if (t < KN * NH) {
    int k = t % KN, hd = t / KN;
    float e = asrc[((size_t)b * NN + nb[k]) * NH + hd] +
              adst[(size_t)bn * NH + hd];
    e = (e >= 0.f) ? e : 0.2f * e;
    attn[k][hd] = e;
  }
  __syncthreads();
  if (t < NH) {
    float mx = -INFINITY;
    for (int k = 0; k < KN; ++k) mx = fmaxf(mx, attn[k][t]);
    float s = 0.f;
    for (int k = 0; k < KN; ++k) {
      float ev = expf(attn[k][t] - mx);
      attn[k][t] = ev;
      s += ev;
    }
    float inv = 1.f / s;
    for (int k = 0; k < KN; ++k) attn[k][t] *= inv;
  }
  __syncthreads();
  if (t < 96) {
    int d = t * 4;
    float4 acc = {0.f, 0.f, 0.f, 0.f};
#pragma unroll 4
    for (int k = 0; k < KN; ++k) {
      const float* hp = h + ((size_t)b * NN + nb[k]) * FF + d;
      float4 aw = *(const float4*)&attn[k][0];
      float4 h0 = *(const float4*)&hp[0];
      float4 h1 = *(const float4*)&hp[HD];
      float4 h2 = *(const float4*)&hp[2 * HD];
      float4 h3 = *(const float4*)&hp[3 * HD];
      acc.x = fmaf(aw.x, h0.x, acc.x); acc.x = fmaf(aw.y, h1.x, acc.x);
      acc.x = fmaf(aw.z, h2.x, acc.x); acc.x = fmaf(aw.w, h3.x, acc.x);
      acc.y = fmaf(aw.x, h0.y, acc.y); acc.y = fmaf(aw.y, h1.y, acc.y);
      acc.y = fmaf(aw.z, h2.y, acc.y); acc.y = fmaf(aw.w, h3.y, acc.y);
      acc.z = fmaf(aw.x, h0.z, acc.z); acc.z = fmaf(aw.y, h1.z, acc.z);
      acc.z = fmaf(aw.z, h2.z, acc.z); acc.z = fmaf(aw.w, h3.z, acc.z);
      acc.w = fmaf(aw.x, h0.w, acc.w); acc.w = fmaf(aw.y, h1.w, acc.w);
      acc.w = fmaf(aw.z, h2.w, acc.w); acc.w = fmaf(aw.w, h3.w, acc.w);
    }
    float o[4] = {acc.x, acc.y, acc.z, acc.w};
    float4 r;
    float* rp = (float*)&r;
#pragma unroll
    for (int j = 0; j < 4; ++j) {
      int dd = d + j;
      float val = o[j] * 0.25f + bg[dd];
      float sc = bng[dd] / sqrtf(bng[3 * HD + dd] + BN_EPS);
      val = (val - bng[2 * HD + dd]) * sc + bng[HD + dd];
      val = 0.5f * val * (1.f + erff(val * 0.7071067811865475f));
      rp[j] = val;
    }
    *(float4*)&g[(size_t)bn * HD + d] = r;
  }
}

// ---------------------------------------------------------------- fc2 + BN + residual + transpose-out (direct stage from gT/W2T)
__global__ __launch_bounds__(256) void k_fc2(
    const float* __restrict__ gT, const float* __restrict__ W2T,
    const float* __restrict__ b2, const float* __restrict__ bn2,
    const float* __restrict__ x, float* __restrict__ out) {
  int nt = blockIdx.x, ct = blockIdx.y, b = blockIdx.z;
  int n0 = nt * 64, c0 = ct * 64;
  __shared__ float As[64][64];   // [k][n]
  __shared__ float Bs[64][64];   // [k][c]
  int t = threadIdx.x;
  int tx = t & 15, ty = t >> 4;
  float4 acc[4];
#pragma unroll
  for (int i = 0; i < 4; ++i) acc[i] = {0.f, 0.f, 0.f, 0.f};
  for (int k0 = 0; k0 < HD; k0 += 64) {
    __syncthreads();
#pragma unroll
    for (int i = 0; i < 4; ++i) {
      int fi = i * 256 + t;
      int r = fi >> 4, q = fi & 15;
      *(float4*)&As[r][q * 4] =
          *(const float4*)&gT[((size_t)b * HD + k0 + r) * NN + n0 + q * 4];
      *(float4*)&Bs[r][q * 4] =
          *(const float4*)&W2T[(size_t)(k0 + r) * Cc + c0 + q * 4];
    }
    __syncthreads();
#pragma unroll 8
    for (int k = 0; k < 64; ++k) {
      float4 a = *(const float4*)&As[k][ty * 4];
      float4 bv = *(const float4*)&Bs[k][tx * 4];
      FMA_ROW(acc[0], a.x, bv)
      FMA_ROW(acc[1], a.y, bv)
      FMA_ROW(acc[2], a.z, bv)
      FMA_ROW(acc[3], a.w, bv)
    }
  }
  float accm[4][4] = {
      {acc[0].x, acc[0].y, acc[0].z, acc[0].w},
      {acc[1].x, acc[1].y, acc[1].z, acc[1].w},
      {acc[2].x, acc[2].y, acc[2].z, acc[2].w},
      {acc[3].x, acc[3].y, acc[3].z, acc[3].w}};
#pragma unroll
  for (int jj = 0; jj < 4; ++jj) {
    int c = c0 + tx * 4 + jj;
    float s  = bn2[c] / sqrtf(bn2[3 * Cc + c] + BN_EPS);
    float mm = bn2[2 * Cc + c];
    float be = bn2[Cc + c];
    float bias = b2[c];
    float4 res = *(const float4*)&x[((size_t)b * Cc + c) * NN + n0 + ty * 4];
    float4 o;
    o.x = (accm[0][jj] + bias - mm) * s + be + res.x;
    o.y = (accm[1][jj] + bias - mm) * s + be + res.y;
    o.z = (accm[2][jj] + bias - mm) * s + be + res.z;
    o.w = (accm[3][jj] + bias - mm) * s + be + res.w;
    *(float4*)&out[((size_t)b * Cc + c) * NN + n0 + ty * 4] = o;
  }
}

extern "C" void kernel_launch(void* const* d_in, const int* in_sizes, int n_in,
                              void* d_out, int out_size, void* d_ws, size_t ws_size,
                              hipStream_t stream) {
  const float* x       = (const float*)d_in[0];
  const float* W1      = (const float*)d_in[1];
  const float* b1      = (const float*)d_in[2];
  const float* bn1     = (const float*)d_in[3];
  const float* Wg      = (const float*)d_in[4];
  const float* att_src = (const float*)d_in[5];
  const float* att_dst = (const float*)d_in[6];
  const float* bg      = (const float*)d_in[7];
  const float* bng     = (const float*)d_in[8];
  const float* W2      = (const float*)d_in[9];
  const float* b2      = (const float*)d_in[10];
  const float* bn2     = (const float*)d_in[11];
  float* out = (float*)d_out;

  float* ws   = (float*)d_ws;
  float* y    = ws;                        // 786432
  float* h    = y + 786432;                // 6291456
  float* sq   = h + 6291456;               // 4096
  float* asrc = sq + 4096;                 // 16384
  float* adst = asrc + 16384;              // 16384
  float* dist = adst + 16384;              // 4194304
  float* g    = dist;                      // 1572864 (reuse; dist dead after topk)
  int*   idx  = (int*)(dist + 4194304);    // 65536 ints
  float* yT   = dist + 4194304 + 65536;    // 786432  [b][k][n]
  float* gT   = yT + 786432;               // 1572864 [b][d][n]
  float* W1T  = gT + 1572864;              // 36864   [k][c]
  float* W2T  = W1T + 36864;               // 73728   [k][c]

  k_tr<<<dim3(6, 6, 1), 256, 0, stream>>>(W1, W1T, Cc, Cc);
  k_tr<<<dim3(12, 6, 1), 256, 0, stream>>>(W2, W2T, Cc, HD);
  k_fc1<<<dim3(16, 3, 4), 256, 0, stream>>>(x, W1T, b1, bn1, y);
  k_tr<<<dim3(6, 32, 4), 256, 0, stream>>>(y, yT, NN, Cc);
  k_sq<<<Bb * NN, 64, 0, stream>>>(y, sq);
  k_hgemm<<<dim3(32, 24), 256, 0, stream>>>(yT, Wg, h);
  k_attn_coef<<<Bb * NN, 256, 0, stream>>>(h, att_src, att_dst, asrc, adst);
  k_dist<<<dim3(16, 8, 4), 256, 0, stream>>>(yT, sq, dist);
  k_topk<<<Bb * NN, 64, 0, stream>>>(dist, idx);
  k_gat<<<Bb * NN, 128, 0, stream>>>(h, asrc, adst, idx, bg, bng, g);
  k_tr<<<dim3(12, 32, 4), 256, 0, stream>>>(g, gT, NN, HD);
  k_fc2<<<dim3(16, 3, 4), 256, 0, stream>>>(gT, W2T, b2, bn2, x, out);
}

// Round 9
// 148.250 us; speedup vs baseline: 1.2938x; 1.2018x over previous
//
#include <hip/hip_runtime.h>
#include <math.h>

#define Bb 4
#define Cc 192
#define NN 1024
#define HD 384
#define NH 4
#define FF 1536   // NH*HD
#define KN 16
#define BN_EPS 1e-5f

typedef __attribute__((ext_vector_type(8))) short bf16x8;
typedef __attribute__((ext_vector_type(4))) float f32x4;

__device__ inline float b2f(ushort u) {
  return __uint_as_float(((unsigned)u) << 16);
}
__device__ inline ushort f2b(float f) {
  unsigned v = __float_as_uint(f);
  return (ushort)((v + 0x7fffu + ((v >> 16) & 1u)) >> 16);
}

// one row of register-tile FMAs: acc.{x,y,z,w} += av * b.{x,y,z,w}
#define FMA_ROW(ACC, AV, B) \
  ACC.x = fmaf(AV, B.x, ACC.x); ACC.y = fmaf(AV, B.y, ACC.y); \
  ACC.z = fmaf(AV, B.z, ACC.z); ACC.w = fmaf(AV, B.w, ACC.w);

// ---------------------------------------------------------------- weight prep: W1T, W2T (fp32), WgT (bf16)
// 32x33 LDS tile transpose; block id selects matrix.
__global__ __launch_bounds__(256) void k_prep(
    const float* __restrict__ W1, const float* __restrict__ W2,
    const float* __restrict__ Wg, float* __restrict__ W1T,
    float* __restrict__ W2T, ushort* __restrict__ WgTb) {
  __shared__ float tile[32][33];
  int id = blockIdx.x;
  const float* in; int R, C, cx, cy;
  float* outf = nullptr; ushort* outb = nullptr;
  if (id < 36)       { in = W1; R = Cc; C = Cc;   cx = id % 6;        cy = id / 6;        outf = W1T; }
  else if (id < 108) { int q = id - 36;  in = W2; R = Cc; C = HD;  cx = q % 12; cy = q / 12; outf = W2T; }
  else               { int q = id - 108; in = Wg; R = Cc; C = FF;  cx = q % 48; cy = q / 48; outb = WgTb; }
  int c0 = cx * 32, r0 = cy * 32;
  int tx = threadIdx.x & 31, ty = threadIdx.x >> 5;
#pragma unroll
  for (int i = 0; i < 4; ++i) {
    int r = ty + i * 8;
    tile[r][tx] = in[(size_t)(r0 + r) * C + c0 + tx];
  }
  __syncthreads();
#pragma unroll
  for (int i = 0; i < 4; ++i) {
    int r = ty + i * 8;
    float v = tile[tx][r];
    if (outf) outf[(size_t)(c0 + r) * R + r0 + tx] = v;
    else      outb[(size_t)(c0 + r) * R + r0 + tx] = f2b(v);
  }
}

// ---------------------------------------------------------------- fc1 + BN (bit-frozen math; also emits yb bf16)
__global__ __launch_bounds__(256) void k_fc1(
    const float* __restrict__ x, const float* __restrict__ W1T,
    const float* __restrict__ b1, const float* __restrict__ bn1,
    float* __restrict__ y, ushort* __restrict__ yb) {
  int nt = blockIdx.x, ct = blockIdx.y, b = blockIdx.z;
  int n0 = nt * 64, ct64 = ct * 64;
  __shared__ float As[64][64];   // [k][n]
  __shared__ float Bs[64][64];   // [k][c]
  int t = threadIdx.x;
  int tx = t & 15, ty = t >> 4;
  float4 acc[4];
#pragma unroll
  for (int i = 0; i < 4; ++i) acc[i] = {0.f, 0.f, 0.f, 0.f};
  for (int k0 = 0; k0 < Cc; k0 += 64) {
    __syncthreads();
#pragma unroll
    for (int i = 0; i < 4; ++i) {
      int fi = i * 256 + t;
      int r = fi >> 4, q = fi & 15;
      *(float4*)&As[r][q * 4] =
          *(const float4*)&x[((size_t)b * Cc + k0 + r) * NN + n0 + q * 4];
      *(float4*)&Bs[r][q * 4] =
          *(const float4*)&W1T[(size_t)(k0 + r) * Cc + ct64 + q * 4];
    }
    __syncthreads();
#pragma unroll 8
    for (int k = 0; k < 64; ++k) {
      float4 a = *(const float4*)&As[k][ty * 4];
      float4 bv = *(const float4*)&Bs[k][tx * 4];
      FMA_ROW(acc[0], a.x, bv)
      FMA_ROW(acc[1], a.y, bv)
      FMA_ROW(acc[2], a.z, bv)
      FMA_ROW(acc[3], a.w, bv)
    }
  }
  float s[4], mm[4], be[4], bias[4];
#pragma unroll
  for (int jj = 0; jj < 4; ++jj) {
    int c = ct64 + tx * 4 + jj;
    s[jj]    = bn1[c] / sqrtf(bn1[3 * Cc + c] + BN_EPS);
    mm[jj]   = bn1[2 * Cc + c];
    be[jj]   = bn1[Cc + c];
    bias[jj] = b1[c];
  }
  float accm[4][4] = {
      {acc[0].x, acc[0].y, acc[0].z, acc[0].w},
      {acc[1].x, acc[1].y, acc[1].z, acc[1].w},
      {acc[2].x, acc[2].y, acc[2].z, acc[2].w},
      {acc[3].x, acc[3].y, acc[3].z, acc[3].w}};
#pragma unroll
  for (int ii = 0; ii < 4; ++ii) {
    int n = n0 + ty * 4 + ii;
    float4 o;
    o.x = (accm[ii][0] + bias[0] - mm[0]) * s[0] + be[0];
    o.y = (accm[ii][1] + bias[1] - mm[1]) * s[1] + be[1];
    o.z = (accm[ii][2] + bias[2] - mm[2]) * s[2] + be[2];
    o.w = (accm[ii][3] + bias[3] - mm[3]) * s[3] + be[3];
    *(float4*)&y[((size_t)b * NN + n) * Cc + ct64 + tx * 4] = o;
    ushort4 ob = {f2b(o.x), f2b(o.y), f2b(o.z), f2b(o.w)};
    *(ushort4*)&yb[((size_t)b * NN + n) * Cc + ct64 + tx * 4] = ob;
  }
}

// ---------------------------------------------------------------- generic 32x32 tiled transpose (fp32)
__global__ __launch_bounds__(256) void k_tr(const float* __restrict__ in,
                                            float* __restrict__ out,
                                            int R, int C) {
  __shared__ float tile[32][33];
  int c0 = blockIdx.x * 32, r0 = blockIdx.y * 32;
  const float* ip = in + (size_t)blockIdx.z * R * C;
  float* op = out + (size_t)blockIdx.z * R * C;
  int tx = threadIdx.x & 31, ty = threadIdx.x >> 5;
#pragma unroll
  for (int i = 0; i < 4; ++i) {
    int r = ty + i * 8;
    tile[r][tx] = ip[(size_t)(r0 + r) * C + c0 + tx];
  }
  __syncthreads();
#pragma unroll
  for (int i = 0; i < 4; ++i) {
    int r = ty + i * 8;
    op[(size_t)(c0 + r) * R + r0 + tx] = tile[tx][r];
  }
}

// ---------------------------------------------------------------- row sums of y^2 (bit-frozen)
__global__ __launch_bounds__(64) void k_sq(const float* __restrict__ y,
                                           float* __restrict__ sq) {
  int bn = blockIdx.x;
  int lane = threadIdx.x;
  const float* yp = y + (size_t)bn * Cc;
  float s = 0.f;
  for (int k = lane; k < Cc; k += 64) { float v = yp[k]; s = fmaf(v, v, s); }
#pragma unroll
  for (int off = 32; off; off >>= 1) s += __shfl_down(s, off);
  if (lane == 0) sq[bn] = s;
}

// ---------------------------------------------------------------- h = y @ Wg via bf16 MFMA -> hb (bf16)
// 128x128 block tile, 4 waves (2x2), each wave 64x64 = 4x4 mfma_16x16x32 frags.
__global__ __launch_bounds__(256) void k_hgemm_mfma(
    const ushort* __restrict__ yb, const ushort* __restrict__ WgTb,
    ushort* __restrict__ hb) {
  int r0 = blockIdx.x * 128, c0 = blockIdx.y * 128;
  __shared__ ushort Al[128][72];   // [row][k], 144B rows (9x16B: 2-way banks)
  __shared__ ushort Bl[128][72];   // [col][k]
  int t = threadIdx.x;
  int w = t >> 6, l = t & 63;
  int wr = w >> 1, wc = w & 1;
  f32x4 acc[4][4];
#pragma unroll
  for (int mt = 0; mt < 4; ++mt)
#pragma unroll
    for (int nt = 0; nt < 4; ++nt) acc[mt][nt] = {0.f, 0.f, 0.f, 0.f};
  for (int k0 = 0; k0 < Cc; k0 += 64) {
    __syncthreads();
#pragma unroll
    for (int i = 0; i < 4; ++i) {          // 1024 16B-units per operand
      int u = i * 256 + t;
      int r = u >> 3, ko = (u & 7) * 8;
      *(int4*)&Al[r][ko] = *(const int4*)&yb[(size_t)(r0 + r) * Cc + k0 + ko];
      *(int4*)&Bl[r][ko] = *(const int4*)&WgTb[(size_t)(c0 + r) * Cc + k0 + ko];
    }
    __syncthreads();
#pragma unroll
    for (int ks = 0; ks < 2; ++ks) {
      bf16x8 af[4], bfr[4];
#pragma unroll
      for (int mt = 0; mt < 4; ++mt)
        af[mt] = *(const bf16x8*)&Al[wr * 64 + mt * 16 + (l & 15)][ks * 32 + (l >> 4) * 8];
#pragma unroll
      for (int nt = 0; nt < 4; ++nt)
        bfr[nt] = *(const bf16x8*)&Bl[wc * 64 + nt * 16 + (l & 15)][ks * 32 + (l >> 4) * 8];
#pragma unroll
      for (int mt = 0; mt < 4; ++mt)
#pragma unroll
        for (int nt = 0; nt < 4; ++nt)
          acc[mt][nt] = __builtin_amdgcn_mfma_f32_16x16x32_bf16(
              af[mt], bfr[nt], acc[mt][nt], 0, 0, 0);
    }
  }
  int col_l = l & 15, rg = l >> 4;
#pragma unroll
  for (int mt = 0; mt < 4; ++mt)
#pragma unroll
    for (int nt = 0; nt < 4; ++nt) {
      int col = c0 + wc * 64 + nt * 16 + col_l;
#pragma unroll
      for (int j = 0; j < 4; ++j) {
        int row = r0 + wr * 64 + mt * 16 + rg * 4 + j;
        hb[(size_t)row * FF + col] = f2b(acc[mt][nt][j]);
      }
    }
}

// ---------------------------------------------------------------- a_src / a_dst from bf16 h
__global__ __launch_bounds__(256) void k_attn_coef(
    const ushort* __restrict__ hb, const float* __restrict__ att_src,
    const float* __restrict__ att_dst, float* __restrict__ asrc,
    float* __restrict__ adst) {
  int bn = blockIdx.x;
  int head = threadIdx.x / 64, lane = threadIdx.x % 64;
  const ushort* hp = hb + (size_t)bn * FF + head * HD;
  const float* as = att_src + head * HD;
  const float* ad = att_dst + head * HD;
  float s1 = 0.f, s2 = 0.f;
  for (int d = lane; d < HD; d += 64) {
    float v = b2f(hp[d]);
    s1 = fmaf(v, as[d], s1);
    s2 = fmaf(v, ad[d], s2);
  }
#pragma unroll
  for (int off = 32; off; off >>= 1) {
    s1 += __shfl_down(s1, off);
    s2 += __shfl_down(s2, off);
  }
  if (lane == 0) {
    asrc[bn * NH + head] = s1;
    adst[bn * NH + head] = s2;
  }
}

// ---------------------------------------------------------------- pairwise distances (bit-frozen; from yT fp32)
__global__ __launch_bounds__(256) void k_dist(const float* __restrict__ yT,
                                              const float* __restrict__ sq,
                                              float* __restrict__ dist) {
  int b = blockIdx.z;
  int n0 = blockIdx.y * 128, m0 = blockIdx.x * 64;
  __shared__ float As[64][128];
  __shared__ float Bs[64][64];
  const float* ytb = yT + (size_t)b * Cc * NN;
  int t = threadIdx.x;
  int tx = t & 15, ty = t >> 4;
  float4 acc[8];
#pragma unroll
  for (int i = 0; i < 8; ++i) acc[i] = {0.f, 0.f, 0.f, 0.f};
  for (int k0 = 0; k0 < Cc; k0 += 64) {
    __syncthreads();
#pragma unroll
    for (int i = 0; i < 8; ++i) {
      int fi = i * 256 + t;
      int kk = fi >> 5, n4 = fi & 31;
      *(float4*)&As[kk][n4 * 4] =
          *(const float4*)&ytb[(size_t)(k0 + kk) * NN + n0 + n4 * 4];
    }
#pragma unroll
    for (int i = 0; i < 4; ++i) {
      int fi = i * 256 + t;
      int kk = fi >> 4, m4 = fi & 15;
      *(float4*)&Bs[kk][m4 * 4] =
          *(const float4*)&ytb[(size_t)(k0 + kk) * NN + m0 + m4 * 4];
    }
    __syncthreads();
#pragma unroll 8
    for (int k = 0; k < 64; ++k) {
      float4 a0 = *(const float4*)&As[k][ty * 4];
      float4 a1 = *(const float4*)&As[k][64 + ty * 4];
      float4 b4 = *(const float4*)&Bs[k][tx * 4];
      FMA_ROW(acc[0], a0.x, b4)
      FMA_ROW(acc[1], a0.y, b4)
      FMA_ROW(acc[2], a0.z, b4)
      FMA_ROW(acc[3], a0.w, b4)
      FMA_ROW(acc[4], a1.x, b4)
      FMA_ROW(acc[5], a1.y, b4)
      FMA_ROW(acc[6], a1.z, b4)
      FMA_ROW(acc[7], a1.w, b4)
    }
  }
#pragma unroll
  for (int ii = 0; ii < 8; ++ii) {
    int n = n0 + ((ii < 4) ? (ty * 4 + ii) : (64 + ty * 4 + ii - 4));
    float sn = sq[b * NN + n];
    int mbase = m0 + tx * 4;
    float av[4] = {acc[ii].x, acc[ii].y, acc[ii].z, acc[ii].w};
    float4 o;
    o.x = sn + sq[b * NN + mbase + 0] - 2.f * av[0];
    o.y = sn + sq[b * NN + mbase + 1] - 2.f * av[1];
    o.z = sn + sq[b * NN + mbase + 2] - 2.f * av[2];
    o.w = sn + sq[b * NN + mbase + 3] - 2.f * av[3];
    *(float4*)&dist[((size_t)b * NN + n) * NN + mbase] = o;
  }
}

// ---------------------------------------------------------------- top-16 smallest per row (bit-frozen)
__global__ __launch_bounds__(64) void k_topk(const float* __restrict__ dist,
                                             int* __restrict__ idx) {
  int bn = blockIdx.x;
  int lane = threadIdx.x;
  const float4* dp = (const float4*)(dist + (size_t)bn * NN);
  float dv[16];
#pragma unroll
  for (int q = 0; q < 4; ++q) {
    float4 v = dp[lane + 64 * q];
    dv[q * 4 + 0] = v.x; dv[q * 4 + 1] = v.y;
    dv[q * 4 + 2] = v.z; dv[q * 4 + 3] = v.w;
  }
  for (int sel = 0; sel < KN; ++sel) {
    float bv = INFINITY;
    int bi = 0x7fffffff;
#pragma unroll
    for (int q = 0; q < 4; ++q)
#pragma unroll
      for (int j = 0; j < 4; ++j) {
        int m = (lane + 64 * q) * 4 + j;
        float v = dv[q * 4 + j];
        if (v < bv || (v == bv && m < bi)) { bv = v; bi = m; }
      }
#pragma unroll
    for (int off = 32; off; off >>= 1) {
      float ov = __shfl_xor(bv, off);
      int oi   = __shfl_xor(bi, off);
      if (ov < bv || (ov == bv && oi < bi)) { bv = ov; bi = oi; }
    }
    if (lane == 0) idx[bn * KN + sel] = bi;
#pragma unroll
    for (int q = 0; q < 4; ++q)
#pragma unroll
      for (int j = 0; j < 4; ++j)
        if ((lane + 64 * q) * 4 + j == bi) dv[q * 4 + j] = INFINITY;
  }
}

// ---------------------------------------------------------------- GAT aggregate + BN + GELU (gathers bf16 h)
__global__ __launch_bounds__(128, 4) void k_gat(
    const ushort* __restrict__ hb, const float* __restrict__ asrc,
    const float* __restrict__ adst, const int* __restrict__ idx,
    const float* __restrict__ bg, const float* __restrict__ bng,
    float* __restrict__ g) {
  int bid = blockIdx.x;
  int bn = (bid & 7) * (Bb * NN / 8) + (bid >> 3);   // bijective XCD swizzle
  int b = bn / NN;
  __shared__ int nb[KN];
  __shared__ float attn[KN][NH];
  int t = threadIdx.x;
  if (t < KN) nb[t] = idx[bn * KN + t];
  __syncthreads();
  if (t < KN * NH) {
    int k = t % KN, hd = t / KN;
    float e = asrc[((size_t)b * NN + nb[k]) * NH + hd] +
              adst[(size_t)bn * NH + hd];
    e = (e >= 0.f) ? e : 0.2f * e;
    attn[k][hd] = e;
  }
  __syncthreads();
  if (t < NH) {
    float mx = -INFINITY;
    for (int k = 0; k < KN; ++k) mx = fmaxf(mx, attn[k][t]);
    float s = 0.f;
    for (int k = 0; k < KN; ++k) {
      float ev = expf(attn[k][t] - mx);
      attn[k][t] = ev;
      s += ev;
    }
    float inv = 1.f / s;
    for (int k = 0; k < KN; ++k) attn[k][t] *= inv;
  }
  __syncthreads();
  if (t < 96) {
    int d = t * 4;
    float4 acc = {0.f, 0.f, 0.f, 0.f};
#pragma unroll 4
    for (int k = 0; k < KN; ++k) {
      const ushort* hp = hb + ((size_t)b * NN + nb[k]) * FF + d;
      float4 aw = *(const float4*)&attn[k][0];
      ushort4 u0 = *(const ushort4*)&hp[0];
      ushort4 u1 = *(const ushort4*)&hp[HD];
      ushort4 u2 = *(const ushort4*)&hp[2 * HD];
      ushort4 u3 = *(const ushort4*)&hp[3 * HD];
      float4 h0 = {b2f(u0.x), b2f(u0.y), b2f(u0.z), b2f(u0.w)};
      float4 h1 = {b2f(u1.x), b2f(u1.y), b2f(u1.z), b2f(u1.w)};
      float4 h2 = {b2f(u2.x), b2f(u2.y), b2f(u2.z), b2f(u2.w)};
      float4 h3 = {b2f(u3.x), b2f(u3.y), b2f(u3.z), b2f(u3.w)};
      acc.x = fmaf(aw.x, h0.x, acc.x); acc.x = fmaf(aw.y, h1.x, acc.x);
      acc.x = fmaf(aw.z, h2.x, acc.x); acc.x = fmaf(aw.w, h3.x, acc.x);
      acc.y = fmaf(aw.x, h0.y, acc.y); acc.y = fmaf(aw.y, h1.y, acc.y);
      acc.y = fmaf(aw.z, h2.y, acc.y); acc.y = fmaf(aw.w, h3.y, acc.y);
      acc.z = fmaf(aw.x, h0.z, acc.z); acc.z = fmaf(aw.y, h1.z, acc.z);
      acc.z = fmaf(aw.z, h2.z, acc.z); acc.z = fmaf(aw.w, h3.z, acc.z);
      acc.w = fmaf(aw.x, h0.w, acc.w); acc.w = fmaf(aw.y, h1.w, acc.w);
      acc.w = fmaf(aw.z, h2.w, acc.w); acc.w = fmaf(aw.w, h3.w, acc.w);
    }
    float o[4] = {acc.x, acc.y, acc.z, acc.w};
    float4 r;
    float* rp = (float*)&r;
#pragma unroll
    for (int j = 0; j < 4; ++j) {
      int dd = d + j;
      float val = o[j] * 0.25f + bg[dd];
      float sc = bng[dd] / sqrtf(bng[3 * HD + dd] + BN_EPS);
      val = (val - bng[2 * HD + dd]) * sc + bng[HD + dd];
      val = 0.5f * val * (1.f + erff(val * 0.7071067811865475f));
      rp[j] = val;
    }
    *(float4*)&g[(size_t)bn * HD + d] = r;
  }
}

// ---------------------------------------------------------------- fc2 + BN + residual + transpose-out
__global__ __launch_bounds__(256) void k_fc2(
    const float* __restrict__ gT, const float* __restrict__ W2T,
    const float* __restrict__ b2, const float* __restrict__ bn2,
    const float* __restrict__ x, float* __restrict__ out) {
  int nt = blockIdx.x, ct = blockIdx.y, b = blockIdx.z;
  int n0 = nt * 64, c0 = ct * 64;
  __shared__ float As[64][64];
  __shared__ float Bs[64][64];
  int t = threadIdx.x;
  int tx = t & 15, ty = t >> 4;
  float4 acc[4];
#pragma unroll
  for (int i = 0; i < 4; ++i) acc[i] = {0.f, 0.f, 0.f, 0.f};
  for (int k0 = 0; k0 < HD; k0 += 64) {
    __syncthreads();
#pragma unroll
    for (int i = 0; i < 4; ++i) {
      int fi = i * 256 + t;
      int r = fi >> 4, q = fi & 15;
      *(float4*)&As[r][q * 4] =
          *(const float4*)&gT[((size_t)b * HD + k0 + r) * NN + n0 + q * 4];
      *(float4*)&Bs[r][q * 4] =
          *(const float4*)&W2T[(size_t)(k0 + r) * Cc + c0 + q * 4];
    }
    __syncthreads();
#pragma unroll 8
    for (int k = 0; k < 64; ++k) {
      float4 a = *(const float4*)&As[k][ty * 4];
      float4 bv = *(const float4*)&Bs[k][tx * 4];
      FMA_ROW(acc[0], a.x, bv)
      FMA_ROW(acc[1], a.y, bv)
      FMA_ROW(acc[2], a.z, bv)
      FMA_ROW(acc[3], a.w, bv)
    }
  }
  float accm[4][4] = {
      {acc[0].x, acc[0].y, acc[0].z, acc[0].w},
      {acc[1].x, acc[1].y, acc[1].z, acc[1].w},
      {acc[2].x, acc[2].y, acc[2].z, acc[2].w},
      {acc[3].x, acc[3].y, acc[3].z, acc[3].w}};
#pragma unroll
  for (int jj = 0; jj < 4; ++jj) {
    int c = c0 + tx * 4 + jj;
    float s  = bn2[c] / sqrtf(bn2[3 * Cc + c] + BN_EPS);
    float mm = bn2[2 * Cc + c];
    float be = bn2[Cc + c];
    float bias = b2[c];
    float4 res = *(const float4*)&x[((size_t)b * Cc + c) * NN + n0 + ty * 4];
    float4 o;
    o.x = (accm[0][jj] + bias - mm) * s + be + res.x;
    o.y = (accm[1][jj] + bias - mm) * s + be + res.y;
    o.z = (accm[2][jj] + bias - mm) * s + be + res.z;
    o.w = (accm[3][jj] + bias - mm) * s + be + res.w;
    *(float4*)&out[((size_t)b * Cc + c) * NN + n0 + ty * 4] = o;
  }
}

extern "C" void kernel_launch(void* const* d_in, const int* in_sizes, int n_in,
                              void* d_out, int out_size, void* d_ws, size_t ws_size,
                              hipStream_t stream) {
  const float* x       = (const float*)d_in[0];
  const float* W1      = (const float*)d_in[1];
  const float* b1      = (const float*)d_in[2];
  const float* bn1     = (const float*)d_in[3];
  const float* Wg      = (const float*)d_in[4];
  const float* att_src = (const float*)d_in[5];
  const float* att_dst = (const float*)d_in[6];
  const float* bg      = (const float*)d_in[7];
  const float* bng     = (const float*)d_in[8];
  const float* W2      = (const float*)d_in[9];
  const float* b2      = (const float*)d_in[10];
  const float* bn2     = (const float*)d_in[11];
  float* out = (float*)d_out;

  // workspace layout (float slots)
  float* ws    = (float*)d_ws;
  float* y     = ws;                        // 786432
  float* sq    = y + 786432;                // 4096
  float* asrc  = sq + 4096;                 // 16384
  float* adst  = asrc + 16384;              // 16384
  float* dist  = adst + 16384;              // 4194304
  float* g     = dist;                      // 1572864 (reuse; dist dead after topk)
  int*   idx   = (int*)(dist + 4194304);    // 65536 ints
  float* yT    = dist + 4194304 + 65536;    // 786432
  float* gT    = yT + 786432;               // 1572864
  float* W1T   = gT + 1572864;              // 36864
  float* W2T   = W1T + 36864;               // 73728
  ushort* yb   = (ushort*)(W2T + 73728);    // 786432 ushort  (393216 f-slots)
  ushort* WgTb = (ushort*)(W2T + 73728 + 393216);          // 294912 ushort (147456 f)
  ushort* hb   = (ushort*)(W2T + 73728 + 393216 + 147456); // 6291456 ushort (3145728 f)

  k_prep<<<396, 256, 0, stream>>>(W1, W2, Wg, W1T, W2T, WgTb);
  k_fc1<<<dim3(16, 3, 4), 256, 0, stream>>>(x, W1T, b1, bn1, y, yb);
  k_tr<<<dim3(6, 32, 4), 256, 0, stream>>>(y, yT, NN, Cc);
  k_sq<<<Bb * NN, 64, 0, stream>>>(y, sq);
  k_hgemm_mfma<<<dim3(32, 12), 256, 0, stream>>>(yb, WgTb, hb);
  k_attn_coef<<<Bb * NN, 256, 0, stream>>>(hb, att_src, att_dst, asrc, adst);
  k_dist<<<dim3(16, 8, 4), 256, 0, stream>>>(yT, sq, dist);
  k_topk<<<Bb * NN, 64, 0, stream>>>(dist, idx);
  k_gat<<<Bb * NN, 128, 0, stream>>>(hb, asrc, adst, idx, bg, bng, g);
  k_tr<<<dim3(12, 32, 4), 256, 0, stream>>>(g, gT, NN, HD);
  k_fc2<<<dim3(16, 3, 4), 256, 0, stream>>>(gT, W2T, b2, bn2, x, out);
}